// Round 14
// baseline (858.267 us; speedup 1.0000x reference)
//
#include <hip/hip_runtime.h>
#include <hip/hip_bf16.h>
#include <math.h>
#include <stdint.h>

#define NEGF (-1e30f)
#define LOG2E 1.44269504088896340736f
#define LN2 0.69314718055994530942f

// lp row layout for the CTC scan: 64 lane-groups x 8 bf16 (5 used, 3 pad)
#define LPROW 512

typedef short bf16x8 __attribute__((ext_vector_type(8)));
typedef float f32x4 __attribute__((ext_vector_type(4)));

__device__ __forceinline__ unsigned short f2b(float x) {
  __hip_bfloat16 h = __float2bfloat16(x);
  return *reinterpret_cast<unsigned short*>(&h);
}
__device__ __forceinline__ float b2f(unsigned short u) {
  __hip_bfloat16 h;
  *reinterpret_cast<unsigned short*>(&h) = u;
  return __bfloat162float(h);
}
__device__ __forceinline__ float gelu_exact(float x) {
  return 0.5f * x * (1.0f + erff(x * 0.70710678118654752440f));
}

#if __has_builtin(__builtin_amdgcn_logf)
__device__ __forceinline__ float fast_log2(float x) { return __builtin_amdgcn_logf(x); }
#else
__device__ __forceinline__ float fast_log2(float x) { return log2f(x); }
#endif

// async global->LDS, 16B per lane. LDS dest = wave-uniform base + lane*16;
// global src is per-lane.
__device__ __forceinline__ void gload16(void* lds, const void* g) {
  __builtin_amdgcn_global_load_lds(
      (__attribute__((address_space(1))) void*)(uintptr_t)g,
      (__attribute__((address_space(3))) void*)(unsigned int)(uintptr_t)lds,
      16, 0, 0);
}

// ---------------------------------------------------------------------------
// fp32 -> bf16 elementwise
// ---------------------------------------------------------------------------
__global__ __launch_bounds__(256) void cvt_enc_kernel(
    const float* __restrict__ in, unsigned short* __restrict__ out, long n4)
{
  long i = (long)blockIdx.x * blockDim.x + threadIdx.x;
  const long stride = (long)gridDim.x * blockDim.x;
  for (; i < n4; i += stride) {
    float4 v = ((const float4*)in)[i];
    ushort4 o;
    o.x = f2b(v.x); o.y = f2b(v.y); o.z = f2b(v.z); o.w = f2b(v.w);
    ((ushort4*)out)[i] = o;
  }
}

// ---------------------------------------------------------------------------
// W (K,N) fp32 -> WT (N,K) bf16, 32x32 LDS tile transpose
// ---------------------------------------------------------------------------
__global__ __launch_bounds__(256) void cvt_wt_kernel(
    const float* __restrict__ W, unsigned short* __restrict__ WT, int K, int N)
{
  __shared__ float tile[32][33];
  const int n0 = blockIdx.x * 32, k0 = blockIdx.y * 32;
  const int tx = threadIdx.x, ty = threadIdx.y;  // 32 x 8
#pragma unroll
  for (int i = 0; i < 32; i += 8) {
    int k = k0 + ty + i, n = n0 + tx;
    tile[ty + i][tx] = (k < K && n < N) ? W[(long)k * N + n] : 0.f;
  }
  __syncthreads();
#pragma unroll
  for (int i = 0; i < 32; i += 8) {
    int n = n0 + ty + i, k = k0 + tx;
    if (n < N && k < K) WT[(long)n * K + k] = f2b(tile[tx][ty + i]);
  }
}

// ---------------------------------------------------------------------------
// m97-structure MFMA GEMM: 128x128 tile, BK=32, 256 threads (4 waves, 2x2).
// (unchanged — passing)
// ---------------------------------------------------------------------------
template<int NFULL, int EPI>
__global__ __launch_bounds__(256, 2) void gemm128_kernel(
    const unsigned short* __restrict__ A,
    const unsigned short* __restrict__ WT,
    const float* __restrict__ bias,
    unsigned short* __restrict__ out,
    float2* __restrict__ partials,
    int K)
{
  extern __shared__ char smem[];
  unsigned short* As = (unsigned short*)smem;            // 2 bufs x 4096 shorts
  unsigned short* Bs = (unsigned short*)(smem + 16384);  // 2 bufs x 4096 shorts

  const int tid = threadIdx.x, lane = tid & 63, w = tid >> 6;
  const int wr = w >> 1, wc = w & 1;
  const int cl = lane & 15, g = lane >> 4;
  const int bx = blockIdx.x;
  const long row0 = (long)blockIdx.y * 128;
  const int col0 = bx * 128;

  const int ch0 = w * 64 + lane;
  const int ch1 = 256 + ch0;
  const unsigned short* Ag0 = A + (row0 + (ch0 >> 2)) * K + (ch0 & 3) * 8;
  const unsigned short* Ag1 = A + (row0 + (ch1 >> 2)) * K + (ch1 & 3) * 8;
  const unsigned short* Bg0 = WT + (long)(col0 + (ch0 >> 2)) * K + (ch0 & 3) * 8;
  const unsigned short* Bg1 = WT + (long)(col0 + (ch1 >> 2)) * K + (ch1 & 3) * 8;
  unsigned short* Al0 = As + w * 512;
  unsigned short* Al1 = As + 2048 + w * 512;
  unsigned short* Bl0 = Bs + w * 512;
  unsigned short* Bl1 = Bs + 2048 + w * 512;

#define STAGE(buf, kt)                          \
  do {                                          \
    const int _ko = (kt) * 32;                  \
    gload16(Al0 + (buf) * 4096, Ag0 + _ko);     \
    gload16(Al1 + (buf) * 4096, Ag1 + _ko);     \
    gload16(Bl0 + (buf) * 4096, Bg0 + _ko);     \
    gload16(Bl1 + (buf) * 4096, Bg1 + _ko);     \
  } while (0)

  f32x4 acc[4][4];
#pragma unroll
  for (int mt = 0; mt < 4; ++mt)
#pragma unroll
    for (int nt = 0; nt < 4; ++nt) acc[mt][nt] = (f32x4){0.f, 0.f, 0.f, 0.f};

  const int NKT = K / 32;
  STAGE(0, 0);
  __syncthreads();
  int buf = 0;
  for (int kt = 0; kt < NKT; ++kt) {
    if (kt + 1 < NKT) STAGE(buf ^ 1, kt + 1);
    const unsigned short* Ab = As + buf * 4096;
    const unsigned short* Bb = Bs + buf * 4096;
    bf16x8 af[4], bfr[4];
#pragma unroll
    for (int mt = 0; mt < 4; ++mt)
      af[mt] = *(const bf16x8*)&Ab[(((wr * 64 + mt * 16 + cl) << 2) + g) * 8];
#pragma unroll
    for (int nt = 0; nt < 4; ++nt)
      bfr[nt] = *(const bf16x8*)&Bb[(((wc * 64 + nt * 16 + cl) << 2) + g) * 8];
#pragma unroll
    for (int mt = 0; mt < 4; ++mt)
#pragma unroll
      for (int nt = 0; nt < 4; ++nt)
        acc[mt][nt] = __builtin_amdgcn_mfma_f32_16x16x32_bf16(
            af[mt], bfr[nt], acc[mt][nt], 0, 0, 0);
    __syncthreads();
    buf ^= 1;
  }
#undef STAGE

  float bv[4];
#pragma unroll
  for (int nt = 0; nt < 4; ++nt) bv[nt] = bias[col0 + wc * 64 + nt * 16 + cl];
#pragma unroll
  for (int mt = 0; mt < 4; ++mt)
#pragma unroll
    for (int nt = 0; nt < 4; ++nt)
#pragma unroll
      for (int j = 0; j < 4; ++j) {
        float v = acc[mt][nt][j] + bv[nt];
        if (EPI == 1) v = gelu_exact(v);
        acc[mt][nt][j] = v;
      }

  if (EPI == 2) {
#pragma unroll
    for (int mt = 0; mt < 4; ++mt)
#pragma unroll
      for (int j = 0; j < 4; ++j) {
        float mx = fmaxf(fmaxf(acc[mt][0][j], acc[mt][1][j]),
                         fmaxf(acc[mt][2][j], acc[mt][3][j]));
#pragma unroll
        for (int off = 1; off < 16; off <<= 1)
          mx = fmaxf(mx, __shfl_xor(mx, off));
        float sm = 0.f;
#pragma unroll
        for (int nt = 0; nt < 4; ++nt) sm += expf(acc[mt][nt][j] - mx);
#pragma unroll
        for (int off = 1; off < 16; off <<= 1) sm += __shfl_xor(sm, off);
        if (cl == 0) {
          long m = row0 + wr * 64 + mt * 16 + g * 4 + j;
          partials[m * 16 + bx * 2 + wc] = make_float2(mx, sm);
        }
      }
  }

  unsigned short* Ct = (unsigned short*)smem;  // [128][136]
#pragma unroll
  for (int mt = 0; mt < 4; ++mt)
#pragma unroll
    for (int nt = 0; nt < 4; ++nt)
#pragma unroll
      for (int j = 0; j < 4; ++j)
        Ct[(wr * 64 + mt * 16 + g * 4 + j) * 136 + wc * 64 + nt * 16 + cl] =
            f2b(acc[mt][nt][j]);
  __syncthreads();
  for (int idx = tid; idx < 2048; idx += 256) {
    int r = idx >> 4, ch = idx & 15;
    *(bf16x8*)&out[(row0 + r) * NFULL + col0 + ch * 8] =
        *(const bf16x8*)&Ct[r * 136 + ch * 8];
  }
}

// ---------------------------------------------------------------------------
// LayerNorm in place on bf16, one wave per row
// ---------------------------------------------------------------------------
template<int D>
__global__ __launch_bounds__(256) void ln_bf16_kernel(
    unsigned short* __restrict__ X, const float* __restrict__ g,
    const float* __restrict__ bt, long M)
{
  constexpr int NI = D / 256;
  const int lane = threadIdx.x & 63;
  const int wid = threadIdx.x >> 6;
  const long row = (long)blockIdx.x * 4 + wid;
  if (row >= M) return;

  float v[NI * 4];
  float s = 0.f;
#pragma unroll
  for (int i = 0; i < NI; ++i) {
    ushort4 u = *(const ushort4*)&X[row * D + (i * 64 + lane) * 4];
    v[i * 4 + 0] = b2f(u.x); v[i * 4 + 1] = b2f(u.y);
    v[i * 4 + 2] = b2f(u.z); v[i * 4 + 3] = b2f(u.w);
    s += v[i * 4 + 0] + v[i * 4 + 1] + v[i * 4 + 2] + v[i * 4 + 3];
  }
#pragma unroll
  for (int off = 32; off; off >>= 1) s += __shfl_xor(s, off);
  const float mu = s * (1.0f / D);
  float q = 0.f;
#pragma unroll
  for (int i = 0; i < NI * 4; ++i) { float d = v[i] - mu; q += d * d; }
#pragma unroll
  for (int off = 32; off; off >>= 1) q += __shfl_xor(q, off);
  const float rs = rsqrtf(q * (1.0f / D) + 1e-6f);
#pragma unroll
  for (int i = 0; i < NI; ++i) {
    ushort4 o;
    int c = (i * 64 + lane) * 4;
    o.x = f2b((v[i * 4 + 0] - mu) * rs * g[c + 0] + bt[c + 0]);
    o.y = f2b((v[i * 4 + 1] - mu) * rs * g[c + 1] + bt[c + 1]);
    o.z = f2b((v[i * 4 + 2] - mu) * rs * g[c + 2] + bt[c + 2]);
    o.w = f2b((v[i * 4 + 3] - mu) * rs * g[c + 3] + bt[c + 3]);
    *(ushort4*)&X[row * D + c] = o;
  }
}

// ---------------------------------------------------------------------------
// logz combine + label gather. Stores LINEAR probabilities scaled by 2^10
// as BF16: p'[s] = exp(score[lab] - logz) * 1024. One wave per row m.
// ---------------------------------------------------------------------------
__global__ __launch_bounds__(256) void logz_gather_kernel(
    const unsigned short* __restrict__ scores,  // (M, 1024) bf16
    const float2* __restrict__ partials,        // (M, 16)
    const int* __restrict__ targets,
    unsigned short* __restrict__ lp_ext,        // (B, T, LPROW) bf16
    long Mtot, int T, int B, int L, int S)
{
  const int w = threadIdx.x >> 6, lane = threadIdx.x & 63;
  const long m = (long)blockIdx.x * 4 + w;
  if (m >= Mtot) return;

  float2 pp = partials[m * 16 + (lane & 15)];
  float Mx = pp.x, Sv = pp.y;
#pragma unroll
  for (int off = 1; off < 16; off <<= 1) {
    float Mo = __shfl_xor(Mx, off);
    float So = __shfl_xor(Sv, off);
    float Mn = fmaxf(Mx, Mo);
    Sv = Sv * expf(Mx - Mn) + So * expf(Mo - Mn);
    Mx = Mn;
  }
  const float logz = Mx + logf(Sv);
  const int b = (int)(m % B);
  const int t = (int)(m / B);
  const unsigned short* srow = scores + m * 1024;
  bf16x8 o = {0, 0, 0, 0, 0, 0, 0, 0};
#pragma unroll
  for (int j = 0; j < 5; ++j) {
    int s = lane * 5 + j;
    int lab = ((s & 1) && s < S) ? targets[b * L + (s >> 1)] : 0;
    o[j] = (short)f2b(expf(b2f(srow[lab]) - logz) * 1024.0f);  // p * 2^10
  }
  *(bf16x8*)&lp_ext[((long)b * T + t) * LPROW + lane * 8] = o;
}

// ---------------------------------------------------------------------------
// CTC forward scan, LINEAR DOMAIN, producer/consumer: ONE BLOCK (4 waves)
// per batch element. All 4 waves cooperatively stage the next 32-row chunk
// into LDS via global_load_lds; wave 0 scans the current chunk with an
// EXPLICIT 4-deep ds_read software pipeline (vv[4] ring, fully static
// indices after unroll) so the ~120cy LDS latency is covered by 3 rows of
// compute. One __syncthreads() per chunk drains staging.
// alpha' in registers (5 states/lane), shfl_up neighbor exchange, exact
// power-of-2 renorm every 8 rows. No transcendentals in the loop.
// ---------------------------------------------------------------------------
#define CHUNK 32
__global__ __launch_bounds__(256, 1) void ctc_scan_kernel(
    const unsigned short* __restrict__ pr,  // (B, T, LPROW) bf16: prob * 1024
    const int* __restrict__ targets, const int* __restrict__ inlens,
    const int* __restrict__ tlens, float* __restrict__ partial,
    int T, int B, int L, int S)
{
  extern __shared__ char smem[];  // 2 bufs x 32 rows x 1024 B = 65536
  unsigned short* ring = (unsigned short*)smem;

  const int b = blockIdx.x;
  const int tid = threadIdx.x;
  const int lane = tid & 63;
  const int w = tid >> 6;
  const int s0 = lane * 5;
  const int inlen = inlens[b];
  const int tlen = tlens[b];
  const int send = 2 * tlen;
  const int capT = inlen - 1;

  const unsigned short* pbase = pr + (long)b * T * LPROW;

  bool valid[5];
  float skm[5];  // skip multiplier 0/1
#pragma unroll
  for (int j = 0; j < 5; ++j) {
    int s = s0 + j;
    valid[j] = (s < S);
    float sk = 0.f;
    if (valid[j] && (s & 1) && s >= 3) {
      int lab = targets[b * L + (s >> 1)];
      int lab2 = targets[b * L + (s >> 1) - 1];
      sk = ((lab != 0) && (lab != lab2)) ? 1.f : 0.f;
    }
    skm[j] = sk;
  }

  // init alpha' from row 0 (direct global read)
  float a[5];
  float abv = 0.f, alv = 0.f;
  int corr = 0, corr_cap = 0;
#pragma unroll
  for (int j = 0; j < 5; ++j) {
    int s = s0 + j;
    a[j] = (valid[j] && s <= 1) ? b2f(pbase[lane * 8 + j]) : 0.f;
  }
  if (capT == 0) {
#pragma unroll
    for (int j = 0; j < 5; ++j) {
      int s = s0 + j;
      if (s == send) abv = a[j];
      if (s == send - 1) alv = a[j];
    }
    corr_cap = corr;
  }

  // stage chunk [t0, t0+32) into ring half `bf`: wave w handles rows
  // r = s*4 + w (8 sweeps), one gload16 per row (lane*16 inside the row).
#define STAGE_CHUNK(bf, t0)                                                   \
  do {                                                                        \
    _Pragma("unroll")                                                         \
    for (int s_ = 0; s_ < 8; ++s_) {                                          \
      const int r_ = s_ * 4 + w;                                              \
      if ((t0) + r_ < T)                                                      \
        gload16(ring + (bf) * 16384 + r_ * 512,                               \
                pbase + ((long)(t0) + r_) * 512 + lane * 8);                  \
    }                                                                         \
  } while (0)

#define CTC_PROCESS(vv, tcur)                                                 \
  do {                                                                        \
    float p_[5];                                                              \
    _Pragma("unroll")                                                         \
    for (int j = 0; j < 5; ++j) p_[j] = b2f((unsigned short)(vv)[j]);         \
    float o_m1 = __shfl_up(a[4], 1);                                          \
    float o_m2 = __shfl_up(a[3], 1);                                          \
    if (lane == 0) { o_m1 = 0.f; o_m2 = 0.f; }                                \
    float na[5];                                                              \
    _Pragma("unroll")                                                         \
    for (int j = 0; j < 5; ++j) {                                             \
      float a1 = (j >= 1) ? a[j - 1] : o_m1;                                  \
      float a2 = (j >= 2) ? a[j - 2] : o_m2;                                  \
      float sum = fmaf(skm[j], a2, a[j] + a1);                                \
      na[j] = valid[j] ? sum * p_[j] : 0.f;                                   \
    }                                                                         \
    _Pragma("unroll")                                                         \
    for (int j = 0; j < 5; ++j) a[j] = na[j];                                 \
    if ((tcur) == capT) {                                                     \
      _Pragma("unroll")                                                       \
      for (int j = 0; j < 5; ++j) {                                           \
        int s = s0 + j;                                                       \
        if (s == send) abv = a[j];                                            \
        if (s == send - 1) alv = a[j];                                        \
      }                                                                       \
      corr_cap = corr;                                                        \
    }                                                                         \
  } while (0)

  // exact power-of-2 wave renorm
#define CTC_RENORM                                                            \
  do {                                                                        \
    float mx = fmaxf(fmaxf(fmaxf(a[0], a[1]), fmaxf(a[2], a[3])), a[4]);      \
    _Pragma("unroll")                                                         \
    for (int off = 1; off < 64; off <<= 1)                                    \
      mx = fmaxf(mx, __shfl_xor(mx, off));                                    \
    int e;                                                                    \
    (void)frexpf(mx, &e);  /* mx == 0 -> e = 0 -> no-op */                    \
    float sc = ldexpf(1.f, -e);                                               \
    _Pragma("unroll")                                                         \
    for (int j = 0; j < 5; ++j) a[j] *= sc;                                   \
    corr += e;                                                                \
  } while (0)

  const int nch = (T + CHUNK - 1) / CHUNK;
  STAGE_CHUNK(0, 0);
  __syncthreads();  // chunk 0 resident
  int buf = 0;
  for (int c = 0; c < nch; ++c) {
    if (c + 1 < nch) STAGE_CHUNK(buf ^ 1, (c + 1) * CHUNK);
    if (w == 0) {
      const unsigned short* rb = ring + buf * 16384 + lane * 8;
      const int t0 = c * CHUNK;
      // explicit 4-deep ds_read pipeline (static indices after full unroll)
      bf16x8 vv[4];
      vv[0] = *(const bf16x8*)&rb[0 * 512];
      vv[1] = *(const bf16x8*)&rb[1 * 512];
      vv[2] = *(const bf16x8*)&rb[2 * 512];
#pragma unroll
      for (int r = 0; r < CHUNK; ++r) {
        if (r + 3 < CHUNK) vv[(r + 3) & 3] = *(const bf16x8*)&rb[(r + 3) * 512];
        const int t = t0 + r;
        if (t >= 1 && t < T) CTC_PROCESS(vv[r & 3], t);
        if ((r & 7) == 7) CTC_RENORM;
      }
    }
    __syncthreads();  // drains each wave's stage loads; next chunk resident
    buf ^= 1;
  }

  if (w == 0) {
#pragma unroll
    for (int off = 32; off; off >>= 1) {
      abv = fmaxf(abv, __shfl_xor(abv, off));
      alv = fmaxf(alv, __shfl_xor(alv, off));
    }
    if (lane == 0) {
      // true log2(alpha) = log2(alpha') + corr_cap - 10*inlen
      float l2 = fast_log2(abv + alv) + (float)corr_cap - 10.0f * (float)inlen;
      float loss = -LN2 * l2;
      if (!(loss <= 1e29f)) loss = 0.f;  // zero_infinity (also catches NaN)
      partial[b] = loss / (float)tlen;
    }
  }
}

__global__ void reduce_kernel(const float* __restrict__ partial,
                              float* __restrict__ out, int B)
{
  int lane = threadIdx.x;
  float v = (lane < B) ? partial[lane] : 0.f;
#pragma unroll
  for (int off = 32; off; off >>= 1) v += __shfl_xor(v, off);
  if (lane == 0) out[0] = v / (float)B;
}

// ---------------------------------------------------------------------------
extern "C" void kernel_launch(void* const* d_in, const int* in_sizes, int n_in,
                              void* d_out, int out_size, void* d_ws, size_t ws_size,
                              hipStream_t stream) {
  const float* enc = (const float*)d_in[0];
  const float* Wp  = (const float*)d_in[1];
  const float* bp  = (const float*)d_in[2];
  const float* Wt  = (const float*)d_in[3];
  const float* btr = (const float*)d_in[4];
  const float* lng = (const float*)d_in[5];
  const float* lnb = (const float*)d_in[6];
  const float* Wd  = (const float*)d_in[7];
  const float* bd  = (const float*)d_in[8];
  const int* tgt   = (const int*)d_in[9];
  const int* inl   = (const int*)d_in[10];
  const int* tll   = (const int*)d_in[11];

  const int D = in_sizes[2];              // 768
  const int V = in_sizes[8];              // 1024
  const int B = in_sizes[10];             // 32
  const int L = in_sizes[9] / B;          // 150
  const long M = (long)in_sizes[0] / D;   // T*B = 64000
  const int T = (int)(M / B);             // 2000
  const int S = 2 * L + 1;                // 301

  char* wsb = (char*)d_ws;
  size_t off = 0;
  auto alloc = [&](size_t bytes) { char* p = wsb + off; off += (bytes + 255) & ~(size_t)255; return p; };
  unsigned short* encb   = (unsigned short*)alloc((size_t)M * D * 2);
  char* x1region         = alloc((size_t)M * V * 2);
  unsigned short* X1b    = (unsigned short*)x1region;   // dead after gemm2
  unsigned short* scores = (unsigned short*)x1region;   // written by gemm3
  unsigned short* X2b    = encb;                        // encb dead after gemm1
  unsigned short* LP     = (unsigned short*)alloc((size_t)B * T * LPROW * 2);
  float2* partials       = (float2*)alloc((size_t)M * 16 * sizeof(float2));
  unsigned short* WpT    = (unsigned short*)alloc((size_t)D * D * 2);
  unsigned short* WtT    = (unsigned short*)alloc((size_t)D * D * 2);
  unsigned short* WdT    = (unsigned short*)alloc((size_t)D * V * 2);
  float* partial         = (float*)alloc(256);

  cvt_wt_kernel<<<dim3(D / 32, D / 32), dim3(32, 8), 0, stream>>>(Wp, WpT, D, D);
  cvt_wt_kernel<<<dim3(D / 32, D / 32), dim3(32, 8), 0, stream>>>(Wt, WtT, D, D);
  cvt_wt_kernel<<<dim3(V / 32, D / 32), dim3(32, 8), 0, stream>>>(Wd, WdT, D, V);
  cvt_enc_kernel<<<2048, 256, 0, stream>>>(enc, encb, (long)M * D / 4);

  const size_t smemg = 34816;
  const dim3 g12(D / 128, (unsigned)(M / 128));   // (6, 500)
  const dim3 g3(V / 128, (unsigned)(M / 128));    // (8, 500)

  gemm128_kernel<768, 0><<<g12, 256, smemg, stream>>>(encb, WpT, bp, X1b, nullptr, D);
  gemm128_kernel<768, 1><<<g12, 256, smemg, stream>>>(X1b, WtT, btr, X2b, nullptr, D);
  ln_bf16_kernel<768><<<(int)(M / 4), 256, 0, stream>>>(X2b, lng, lnb, M);
  gemm128_kernel<1024, 2><<<g3, 256, smemg, stream>>>(X2b, WdT, bd, scores, partials, D);

  logz_gather_kernel<<<(int)(M / 4), 256, 0, stream>>>(
      scores, partials, tgt, LP, M, T, B, L, S);
  ctc_scan_kernel<<<B, 256, 65536, stream>>>(LP, tgt, inl, tll, partial, T, B, L, S);
  reduce_kernel<<<1, 64, 0, stream>>>(partial, (float*)d_out, B);
}

// Round 15
// 814.751 us; speedup vs baseline: 1.0534x; 1.0534x over previous
//
#include <hip/hip_runtime.h>
#include <hip/hip_bf16.h>
#include <math.h>
#include <stdint.h>

#define NEGF (-1e30f)
#define LOG2E 1.44269504088896340736f
#define LN2 0.69314718055994530942f

// lp row layout for the CTC scan: 64 lane-groups x 8 bf16 (5 used, 3 pad)
#define LPROW 512

typedef short bf16x8 __attribute__((ext_vector_type(8)));
typedef float f32x4 __attribute__((ext_vector_type(4)));

__device__ __forceinline__ unsigned short f2b(float x) {
  __hip_bfloat16 h = __float2bfloat16(x);
  return *reinterpret_cast<unsigned short*>(&h);
}
__device__ __forceinline__ float b2f(unsigned short u) {
  __hip_bfloat16 h;
  *reinterpret_cast<unsigned short*>(&h) = u;
  return __bfloat162float(h);
}
__device__ __forceinline__ float gelu_exact(float x) {
  return 0.5f * x * (1.0f + erff(x * 0.70710678118654752440f));
}

#if __has_builtin(__builtin_amdgcn_logf)
__device__ __forceinline__ float fast_log2(float x) { return __builtin_amdgcn_logf(x); }
#else
__device__ __forceinline__ float fast_log2(float x) { return log2f(x); }
#endif

// VALU-speed cross-lane helpers (no LDS/ds_bpermute on the critical path)
template<int CTRL>
__device__ __forceinline__ float dpp_shr(float x) {
  // row_shr:N within 16-lane rows; bound_ctrl=1 -> out-of-row reads give 0
  return __int_as_float(__builtin_amdgcn_update_dpp(
      0, __float_as_int(x), 0x110 | CTRL, 0xf, 0xf, true));
}
__device__ __forceinline__ float readlane_f(float x, int l) {
  return __int_as_float(__builtin_amdgcn_readlane(__float_as_int(x), l));
}

// async global->LDS, 16B per lane. LDS dest = wave-uniform base + lane*16;
// global src is per-lane.
__device__ __forceinline__ void gload16(void* lds, const void* g) {
  __builtin_amdgcn_global_load_lds(
      (__attribute__((address_space(1))) void*)(uintptr_t)g,
      (__attribute__((address_space(3))) void*)(unsigned int)(uintptr_t)lds,
      16, 0, 0);
}

// ---------------------------------------------------------------------------
// fp32 -> bf16 elementwise
// ---------------------------------------------------------------------------
__global__ __launch_bounds__(256) void cvt_enc_kernel(
    const float* __restrict__ in, unsigned short* __restrict__ out, long n4)
{
  long i = (long)blockIdx.x * blockDim.x + threadIdx.x;
  const long stride = (long)gridDim.x * blockDim.x;
  for (; i < n4; i += stride) {
    float4 v = ((const float4*)in)[i];
    ushort4 o;
    o.x = f2b(v.x); o.y = f2b(v.y); o.z = f2b(v.z); o.w = f2b(v.w);
    ((ushort4*)out)[i] = o;
  }
}

// ---------------------------------------------------------------------------
// W (K,N) fp32 -> WT (N,K) bf16, 32x32 LDS tile transpose
// ---------------------------------------------------------------------------
__global__ __launch_bounds__(256) void cvt_wt_kernel(
    const float* __restrict__ W, unsigned short* __restrict__ WT, int K, int N)
{
  __shared__ float tile[32][33];
  const int n0 = blockIdx.x * 32, k0 = blockIdx.y * 32;
  const int tx = threadIdx.x, ty = threadIdx.y;  // 32 x 8
#pragma unroll
  for (int i = 0; i < 32; i += 8) {
    int k = k0 + ty + i, n = n0 + tx;
    tile[ty + i][tx] = (k < K && n < N) ? W[(long)k * N + n] : 0.f;
  }
  __syncthreads();
#pragma unroll
  for (int i = 0; i < 32; i += 8) {
    int n = n0 + ty + i, k = k0 + tx;
    if (n < N && k < K) WT[(long)n * K + k] = f2b(tile[tx][ty + i]);
  }
}

// ---------------------------------------------------------------------------
// m97-structure MFMA GEMM: 128x128 tile, BK=32, 256 threads (4 waves, 2x2).
// (unchanged — passing)
// ---------------------------------------------------------------------------
template<int NFULL, int EPI>
__global__ __launch_bounds__(256, 2) void gemm128_kernel(
    const unsigned short* __restrict__ A,
    const unsigned short* __restrict__ WT,
    const float* __restrict__ bias,
    unsigned short* __restrict__ out,
    float2* __restrict__ partials,
    int K)
{
  extern __shared__ char smem[];
  unsigned short* As = (unsigned short*)smem;            // 2 bufs x 4096 shorts
  unsigned short* Bs = (unsigned short*)(smem + 16384);  // 2 bufs x 4096 shorts

  const int tid = threadIdx.x, lane = tid & 63, w = tid >> 6;
  const int wr = w >> 1, wc = w & 1;
  const int cl = lane & 15, g = lane >> 4;
  const int bx = blockIdx.x;
  const long row0 = (long)blockIdx.y * 128;
  const int col0 = bx * 128;

  const int ch0 = w * 64 + lane;
  const int ch1 = 256 + ch0;
  const unsigned short* Ag0 = A + (row0 + (ch0 >> 2)) * K + (ch0 & 3) * 8;
  const unsigned short* Ag1 = A + (row0 + (ch1 >> 2)) * K + (ch1 & 3) * 8;
  const unsigned short* Bg0 = WT + (long)(col0 + (ch0 >> 2)) * K + (ch0 & 3) * 8;
  const unsigned short* Bg1 = WT + (long)(col0 + (ch1 >> 2)) * K + (ch1 & 3) * 8;
  unsigned short* Al0 = As + w * 512;
  unsigned short* Al1 = As + 2048 + w * 512;
  unsigned short* Bl0 = Bs + w * 512;
  unsigned short* Bl1 = Bs + 2048 + w * 512;

#define STAGE(buf, kt)                          \
  do {                                          \
    const int _ko = (kt) * 32;                  \
    gload16(Al0 + (buf) * 4096, Ag0 + _ko);     \
    gload16(Al1 + (buf) * 4096, Ag1 + _ko);     \
    gload16(Bl0 + (buf) * 4096, Bg0 + _ko);     \
    gload16(Bl1 + (buf) * 4096, Bg1 + _ko);     \
  } while (0)

  f32x4 acc[4][4];
#pragma unroll
  for (int mt = 0; mt < 4; ++mt)
#pragma unroll
    for (int nt = 0; nt < 4; ++nt) acc[mt][nt] = (f32x4){0.f, 0.f, 0.f, 0.f};

  const int NKT = K / 32;
  STAGE(0, 0);
  __syncthreads();
  int buf = 0;
  for (int kt = 0; kt < NKT; ++kt) {
    if (kt + 1 < NKT) STAGE(buf ^ 1, kt + 1);
    const unsigned short* Ab = As + buf * 4096;
    const unsigned short* Bb = Bs + buf * 4096;
    bf16x8 af[4], bfr[4];
#pragma unroll
    for (int mt = 0; mt < 4; ++mt)
      af[mt] = *(const bf16x8*)&Ab[(((wr * 64 + mt * 16 + cl) << 2) + g) * 8];
#pragma unroll
    for (int nt = 0; nt < 4; ++nt)
      bfr[nt] = *(const bf16x8*)&Bb[(((wc * 64 + nt * 16 + cl) << 2) + g) * 8];
#pragma unroll
    for (int mt = 0; mt < 4; ++mt)
#pragma unroll
      for (int nt = 0; nt < 4; ++nt)
        acc[mt][nt] = __builtin_amdgcn_mfma_f32_16x16x32_bf16(
            af[mt], bfr[nt], acc[mt][nt], 0, 0, 0);
    __syncthreads();
    buf ^= 1;
  }
#undef STAGE

  float bv[4];
#pragma unroll
  for (int nt = 0; nt < 4; ++nt) bv[nt] = bias[col0 + wc * 64 + nt * 16 + cl];
#pragma unroll
  for (int mt = 0; mt < 4; ++mt)
#pragma unroll
    for (int nt = 0; nt < 4; ++nt)
#pragma unroll
      for (int j = 0; j < 4; ++j) {
        float v = acc[mt][nt][j] + bv[nt];
        if (EPI == 1) v = gelu_exact(v);
        acc[mt][nt][j] = v;
      }

  if (EPI == 2) {
#pragma unroll
    for (int mt = 0; mt < 4; ++mt)
#pragma unroll
      for (int j = 0; j < 4; ++j) {
        float mx = fmaxf(fmaxf(acc[mt][0][j], acc[mt][1][j]),
                         fmaxf(acc[mt][2][j], acc[mt][3][j]));
#pragma unroll
        for (int off = 1; off < 16; off <<= 1)
          mx = fmaxf(mx, __shfl_xor(mx, off));
        float sm = 0.f;
#pragma unroll
        for (int nt = 0; nt < 4; ++nt) sm += expf(acc[mt][nt][j] - mx);
#pragma unroll
        for (int off = 1; off < 16; off <<= 1) sm += __shfl_xor(sm, off);
        if (cl == 0) {
          long m = row0 + wr * 64 + mt * 16 + g * 4 + j;
          partials[m * 16 + bx * 2 + wc] = make_float2(mx, sm);
        }
      }
  }

  unsigned short* Ct = (unsigned short*)smem;  // [128][136]
#pragma unroll
  for (int mt = 0; mt < 4; ++mt)
#pragma unroll
    for (int nt = 0; nt < 4; ++nt)
#pragma unroll
      for (int j = 0; j < 4; ++j)
        Ct[(wr * 64 + mt * 16 + g * 4 + j) * 136 + wc * 64 + nt * 16 + cl] =
            f2b(acc[mt][nt][j]);
  __syncthreads();
  for (int idx = tid; idx < 2048; idx += 256) {
    int r = idx >> 4, ch = idx & 15;
    *(bf16x8*)&out[(row0 + r) * NFULL + col0 + ch * 8] =
        *(const bf16x8*)&Ct[r * 136 + ch * 8];
  }
}

// ---------------------------------------------------------------------------
// LayerNorm in place on bf16, one wave per row
// ---------------------------------------------------------------------------
template<int D>
__global__ __launch_bounds__(256) void ln_bf16_kernel(
    unsigned short* __restrict__ X, const float* __restrict__ g,
    const float* __restrict__ bt, long M)
{
  constexpr int NI = D / 256;
  const int lane = threadIdx.x & 63;
  const int wid = threadIdx.x >> 6;
  const long row = (long)blockIdx.x * 4 + wid;
  if (row >= M) return;

  float v[NI * 4];
  float s = 0.f;
#pragma unroll
  for (int i = 0; i < NI; ++i) {
    ushort4 u = *(const ushort4*)&X[row * D + (i * 64 + lane) * 4];
    v[i * 4 + 0] = b2f(u.x); v[i * 4 + 1] = b2f(u.y);
    v[i * 4 + 2] = b2f(u.z); v[i * 4 + 3] = b2f(u.w);
    s += v[i * 4 + 0] + v[i * 4 + 1] + v[i * 4 + 2] + v[i * 4 + 3];
  }
#pragma unroll
  for (int off = 32; off; off >>= 1) s += __shfl_xor(s, off);
  const float mu = s * (1.0f / D);
  float q = 0.f;
#pragma unroll
  for (int i = 0; i < NI * 4; ++i) { float d = v[i] - mu; q += d * d; }
#pragma unroll
  for (int off = 32; off; off >>= 1) q += __shfl_xor(q, off);
  const float rs = rsqrtf(q * (1.0f / D) + 1e-6f);
#pragma unroll
  for (int i = 0; i < NI; ++i) {
    ushort4 o;
    int c = (i * 64 + lane) * 4;
    o.x = f2b((v[i * 4 + 0] - mu) * rs * g[c + 0] + bt[c + 0]);
    o.y = f2b((v[i * 4 + 1] - mu) * rs * g[c + 1] + bt[c + 1]);
    o.z = f2b((v[i * 4 + 2] - mu) * rs * g[c + 2] + bt[c + 2]);
    o.w = f2b((v[i * 4 + 3] - mu) * rs * g[c + 3] + bt[c + 3]);
    *(ushort4*)&X[row * D + c] = o;
  }
}

// ---------------------------------------------------------------------------
// logz combine + label gather. Stores LINEAR probabilities scaled by 2^10
// as BF16: p'[s] = exp(score[lab] - logz) * 1024, and 0 for pad states
// (s >= S) so they self-annihilate in the scan. One wave per row m.
// ---------------------------------------------------------------------------
__global__ __launch_bounds__(256) void logz_gather_kernel(
    const unsigned short* __restrict__ scores,  // (M, 1024) bf16
    const float2* __restrict__ partials,        // (M, 16)
    const int* __restrict__ targets,
    unsigned short* __restrict__ lp_ext,        // (B, T, LPROW) bf16
    long Mtot, int T, int B, int L, int S)
{
  const int w = threadIdx.x >> 6, lane = threadIdx.x & 63;
  const long m = (long)blockIdx.x * 4 + w;
  if (m >= Mtot) return;

  float2 pp = partials[m * 16 + (lane & 15)];
  float Mx = pp.x, Sv = pp.y;
#pragma unroll
  for (int off = 1; off < 16; off <<= 1) {
    float Mo = __shfl_xor(Mx, off);
    float So = __shfl_xor(Sv, off);
    float Mn = fmaxf(Mx, Mo);
    Sv = Sv * expf(Mx - Mn) + So * expf(Mo - Mn);
    Mx = Mn;
  }
  const float logz = Mx + logf(Sv);
  const int b = (int)(m % B);
  const int t = (int)(m / B);
  const unsigned short* srow = scores + m * 1024;
  bf16x8 o = {0, 0, 0, 0, 0, 0, 0, 0};
#pragma unroll
  for (int j = 0; j < 5; ++j) {
    int s = lane * 5 + j;
    if (s < S) {
      int lab = (s & 1) ? targets[b * L + (s >> 1)] : 0;
      o[j] = (short)f2b(expf(b2f(srow[lab]) - logz) * 1024.0f);  // p * 2^10
    }
  }
  *(bf16x8*)&lp_ext[((long)b * T + t) * LPROW + lane * 8] = o;
}

// ---------------------------------------------------------------------------
// CTC forward scan, LINEAR DOMAIN, producer/consumer: ONE BLOCK (4 waves)
// per batch element. 4 waves stage the next 32-row chunk into LDS via
// global_load_lds; wave 0 scans the current chunk (4-deep ds_read pipeline).
// ALL cross-lane traffic is VALU-speed: neighbor shift = DPP row_shr:1 +
// 3x v_readlane boundary fix (no ds_bpermute); renorm max = DPP prefix-max
// + 4x v_readlane. Exact power-of-2 renorm every 8 rows; no transcendentals.
// ---------------------------------------------------------------------------
#define CHUNK 32
__global__ __launch_bounds__(256, 1) void ctc_scan_kernel(
    const unsigned short* __restrict__ pr,  // (B, T, LPROW) bf16: prob * 1024
    const int* __restrict__ targets, const int* __restrict__ inlens,
    const int* __restrict__ tlens, float* __restrict__ partial,
    int T, int B, int L, int S)
{
  extern __shared__ char smem[];  // 2 bufs x 32 rows x 1024 B = 65536
  unsigned short* ring = (unsigned short*)smem;

  const int b = blockIdx.x;
  const int tid = threadIdx.x;
  const int lane = tid & 63;
  const int w = tid >> 6;
  const int s0 = lane * 5;
  const int inlen = inlens[b];
  const int tlen = tlens[b];
  const int send = 2 * tlen;
  const int capT = inlen - 1;
  const bool is16 = (lane == 16), is32 = (lane == 32), is48 = (lane == 48);

  const unsigned short* pbase = pr + (long)b * T * LPROW;

  float skm[5];  // skip multiplier 0/1
#pragma unroll
  for (int j = 0; j < 5; ++j) {
    int s = s0 + j;
    float sk = 0.f;
    if (s < S && (s & 1) && s >= 3) {
      int lab = targets[b * L + (s >> 1)];
      int lab2 = targets[b * L + (s >> 1) - 1];
      sk = ((lab != 0) && (lab != lab2)) ? 1.f : 0.f;
    }
    skm[j] = sk;
  }

  // init alpha' from row 0 (direct global read; pad states hold 0)
  float a[5];
  float abv = 0.f, alv = 0.f;
  int corr = 0, corr_cap = 0;
#pragma unroll
  for (int j = 0; j < 5; ++j) {
    int s = s0 + j;
    a[j] = (s <= 1) ? b2f(pbase[lane * 8 + j]) : 0.f;
  }
  if (capT == 0) {
#pragma unroll
    for (int j = 0; j < 5; ++j) {
      int s = s0 + j;
      if (s == send) abv = a[j];
      if (s == send - 1) alv = a[j];
    }
    corr_cap = corr;
  }

  // stage chunk [t0, t0+32) into ring half `bf`: wave w handles rows
  // r = s*4 + w (8 sweeps), one gload16 per row (lane*16 inside the row).
#define STAGE_CHUNK(bf, t0)                                                   \
  do {                                                                        \
    _Pragma("unroll")                                                         \
    for (int s_ = 0; s_ < 8; ++s_) {                                          \
      const int r_ = s_ * 4 + w;                                              \
      if ((t0) + r_ < T)                                                      \
        gload16(ring + (bf) * 16384 + r_ * 512,                               \
                pbase + ((long)(t0) + r_) * 512 + lane * 8);                  \
    }                                                                         \
  } while (0)

  // one DP row: all cross-lane via DPP + readlane (VALU speed).
  // o_m1 = alpha[s0-1] (left lane's a[4]); o_m2 = alpha[s0-2] (left a[3]).
#define CTC_PROCESS(vv, tcur)                                                 \
  do {                                                                        \
    float p_[5];                                                              \
    _Pragma("unroll")                                                         \
    for (int j = 0; j < 5; ++j) p_[j] = b2f((unsigned short)(vv)[j]);         \
    float r15 = readlane_f(a[4], 15), r31 = readlane_f(a[4], 31),             \
          r47 = readlane_f(a[4], 47);                                         \
    float q15 = readlane_f(a[3], 15), q31 = readlane_f(a[3], 31),             \
          q47 = readlane_f(a[3], 47);                                         \
    float o_m1 = dpp_shr<1>(a[4]);                                            \
    float o_m2 = dpp_shr<1>(a[3]);                                            \
    o_m1 = is16 ? r15 : o_m1; o_m1 = is32 ? r31 : o_m1;                       \
    o_m1 = is48 ? r47 : o_m1;                                                 \
    o_m2 = is16 ? q15 : o_m2; o_m2 = is32 ? q31 : o_m2;                       \
    o_m2 = is48 ? q47 : o_m2;                                                 \
    float na0 = fmaf(skm[0], o_m2, a[0] + o_m1) * p_[0];                      \
    float na1 = fmaf(skm[1], o_m1, a[1] + a[0]) * p_[1];                      \
    float na2 = fmaf(skm[2], a[0], a[2] + a[1]) * p_[2];                      \
    float na3 = fmaf(skm[3], a[1], a[3] + a[2]) * p_[3];                      \
    float na4 = fmaf(skm[4], a[2], a[4] + a[3]) * p_[4];                      \
    a[0] = na0; a[1] = na1; a[2] = na2; a[3] = na3; a[4] = na4;               \
    if ((tcur) == capT) {                                                     \
      _Pragma("unroll")                                                       \
      for (int j = 0; j < 5; ++j) {                                           \
        int s = s0 + j;                                                       \
        if (s == send) abv = a[j];                                            \
        if (s == send - 1) alv = a[j];                                        \
      }                                                                       \
      corr_cap = corr;                                                        \
    }                                                                         \
  } while (0)

  // exact power-of-2 wave renorm, VALU-only (DPP prefix-max + readlanes)
#define CTC_RENORM                                                            \
  do {                                                                        \
    float m_ = fmaxf(fmaxf(fmaxf(a[0], a[1]), fmaxf(a[2], a[3])), a[4]);      \
    m_ = fmaxf(m_, dpp_shr<1>(m_));                                           \
    m_ = fmaxf(m_, dpp_shr<2>(m_));                                           \
    m_ = fmaxf(m_, dpp_shr<4>(m_));                                           \
    m_ = fmaxf(m_, dpp_shr<8>(m_));                                           \
    float mx = fmaxf(fmaxf(readlane_f(m_, 15), readlane_f(m_, 31)),           \
                     fmaxf(readlane_f(m_, 47), readlane_f(m_, 63)));          \
    int e;                                                                    \
    (void)frexpf(mx, &e);  /* mx == 0 -> e = 0 -> no-op */                    \
    float sc = ldexpf(1.f, -e);                                               \
    _Pragma("unroll")                                                         \
    for (int j = 0; j < 5; ++j) a[j] *= sc;                                   \
    corr += e;                                                                \
  } while (0)

  const int nch = (T + CHUNK - 1) / CHUNK;
  STAGE_CHUNK(0, 0);
  __syncthreads();  // chunk 0 resident
  int buf = 0;
  for (int c = 0; c < nch; ++c) {
    if (c + 1 < nch) STAGE_CHUNK(buf ^ 1, (c + 1) * CHUNK);
    if (w == 0) {
      const unsigned short* rb = ring + buf * 16384 + lane * 8;
      const int t0 = c * CHUNK;
      // 4-deep ds_read pipeline (static indices after full unroll)
      bf16x8 vv[4];
      vv[0] = *(const bf16x8*)&rb[0 * 512];
      vv[1] = *(const bf16x8*)&rb[1 * 512];
      vv[2] = *(const bf16x8*)&rb[2 * 512];
#pragma unroll
      for (int r = 0; r < CHUNK; ++r) {
        if (r + 3 < CHUNK) vv[(r + 3) & 3] = *(const bf16x8*)&rb[(r + 3) * 512];
        const int t = t0 + r;
        if (t >= 1 && t < T) CTC_PROCESS(vv[r & 3], t);
        if ((r & 7) == 7) CTC_RENORM;
      }
    }
    __syncthreads();  // drains each wave's stage loads; next chunk resident
    buf ^= 1;
  }

  if (w == 0) {
#pragma unroll
    for (int off = 32; off; off >>= 1) {
      abv = fmaxf(abv, __shfl_xor(abv, off));
      alv = fmaxf(alv, __shfl_xor(alv, off));
    }
    if (lane == 0) {
      // true log2(alpha) = log2(alpha') + corr_cap - 10*inlen
      float l2 = fast_log2(abv + alv) + (float)corr_cap - 10.0f * (float)inlen;
      float loss = -LN2 * l2;
      if (!(loss <= 1e29f)) loss = 0.f;  // zero_infinity (also catches NaN)
      partial[b] = loss / (float)tlen;
    }
  }
}

__global__ void reduce_kernel(const float* __restrict__ partial,
                              float* __restrict__ out, int B)
{
  int lane = threadIdx.x;
  float v = (lane < B) ? partial[lane] : 0.f;
#pragma unroll
  for (int off = 32; off; off >>= 1) v += __shfl_xor(v, off);
  if (lane == 0) out[0] = v / (float)B;
}

// ---------------------------------------------------------------------------
extern "C" void kernel_launch(void* const* d_in, const int* in_sizes, int n_in,
                              void* d_out, int out_size, void* d_ws, size_t ws_size,
                              hipStream_t stream) {
  const float* enc = (const float*)d_in[0];
  const float* Wp  = (const float*)d_in[1];
  const float* bp  = (const float*)d_in[2];
  const float* Wt  = (const float*)d_in[3];
  const float* btr = (const float*)d_in[4];
  const float* lng = (const float*)d_in[5];
  const float* lnb = (const float*)d_in[6];
  const float* Wd  = (const float*)d_in[7];
  const float* bd  = (const float*)d_in[8];
  const int* tgt   = (const int*)d_in[9];
  const int* inl   = (const int*)d_in[10];
  const int* tll   = (const int*)d_in[11];

  const int D = in_sizes[2];              // 768
  const int V = in_sizes[8];              // 1024
  const int B = in_sizes[10];             // 32
  const int L = in_sizes[9] / B;          // 150
  const long M = (long)in_sizes[0] / D;   // T*B = 64000
  const int T = (int)(M / B);             // 2000
  const int S = 2 * L + 1;                // 301

  char* wsb = (char*)d_ws;
  size_t off = 0;
  auto alloc = [&](size_t bytes) { char* p = wsb + off; off += (bytes + 255) & ~(size_t)255; return p; };
  unsigned short* encb   = (unsigned short*)alloc((size_t)M * D * 2);
  char* x1region         = alloc((size_t)M * V * 2);
  unsigned short* X1b    = (unsigned short*)x1region;   // dead after gemm2
  unsigned short* scores = (unsigned short*)x1region;   // written by gemm3
  unsigned short* X2b    = encb;                        // encb dead after gemm1
  unsigned short* LP     = (unsigned short*)alloc((size_t)B * T * LPROW * 2);
  float2* partials       = (float2*)alloc((size_t)M * 16 * sizeof(float2));
  unsigned short* WpT    = (unsigned short*)alloc((size_t)D * D * 2);
  unsigned short* WtT    = (unsigned short*)alloc((size_t)D * D * 2);
  unsigned short* WdT    = (unsigned short*)alloc((size_t)D * V * 2);
  float* partial         = (float*)alloc(256);

  cvt_wt_kernel<<<dim3(D / 32, D / 32), dim3(32, 8), 0, stream>>>(Wp, WpT, D, D);
  cvt_wt_kernel<<<dim3(D / 32, D / 32), dim3(32, 8), 0, stream>>>(Wt, WtT, D, D);
  cvt_wt_kernel<<<dim3(V / 32, D / 32), dim3(32, 8), 0, stream>>>(Wd, WdT, D, V);
  cvt_enc_kernel<<<2048, 256, 0, stream>>>(enc, encb, (long)M * D / 4);

  const size_t smemg = 34816;
  const dim3 g12(D / 128, (unsigned)(M / 128));   // (6, 500)
  const dim3 g3(V / 128, (unsigned)(M / 128));    // (8, 500)

  gemm128_kernel<768, 0><<<g12, 256, smemg, stream>>>(encb, WpT, bp, X1b, nullptr, D);
  gemm128_kernel<768, 1><<<g12, 256, smemg, stream>>>(X1b, WtT, btr, X2b, nullptr, D);
  ln_bf16_kernel<768><<<(int)(M / 4), 256, 0, stream>>>(X2b, lng, lnb, M);
  gemm128_kernel<1024, 2><<<g3, 256, smemg, stream>>>(X2b, WdT, bd, scores, partials, D);

  logz_gather_kernel<<<(int)(M / 4), 256, 0, stream>>>(
      scores, partials, tgt, LP, M, T, B, L, S);
  ctc_scan_kernel<<<B, 256, 65536, stream>>>(LP, tgt, inl, tll, partial, T, B, L, S);
  reduce_kernel<<<1, 64, 0, stream>>>(partial, (float*)d_out, B);
}

// Round 16
// 806.883 us; speedup vs baseline: 1.0637x; 1.0098x over previous
//
#include <hip/hip_runtime.h>
#include <hip/hip_bf16.h>
#include <math.h>
#include <stdint.h>

#define NEGF (-1e30f)
#define LOG2E 1.44269504088896340736f
#define LN2 0.69314718055994530942f

// lp row layout for the CTC scan: 64 lane-groups x 8 bf16 (5 used, 3 pad)
#define LPROW 512

typedef short bf16x8 __attribute__((ext_vector_type(8)));
typedef float f32x4 __attribute__((ext_vector_type(4)));

__device__ __forceinline__ unsigned short f2b(float x) {
  __hip_bfloat16 h = __float2bfloat16(x);
  return *reinterpret_cast<unsigned short*>(&h);
}
__device__ __forceinline__ float b2f(unsigned short u) {
  __hip_bfloat16 h;
  *reinterpret_cast<unsigned short*>(&h) = u;
  return __bfloat162float(h);
}
__device__ __forceinline__ float gelu_exact(float x) {
  return 0.5f * x * (1.0f + erff(x * 0.70710678118654752440f));
}

#if __has_builtin(__builtin_amdgcn_logf)
__device__ __forceinline__ float fast_log2(float x) { return __builtin_amdgcn_logf(x); }
#else
__device__ __forceinline__ float fast_log2(float x) { return log2f(x); }
#endif

// VALU-speed cross-lane helpers (no LDS/ds_bpermute on the critical path)
template<int CTRL>
__device__ __forceinline__ float dpp_shr(float x) {
  // row_shr:N within 16-lane rows; bound_ctrl=1 -> out-of-row reads give 0
  return __int_as_float(__builtin_amdgcn_update_dpp(
      0, __float_as_int(x), 0x110 | CTRL, 0xf, 0xf, true));
}
__device__ __forceinline__ float readlane_f(float x, int l) {
  return __int_as_float(__builtin_amdgcn_readlane(__float_as_int(x), l));
}

// inline-asm 16B global load: issue point is PINNED (asm volatile); result is
// valid only after a matching s_waitcnt vmcnt(N) (also asm volatile).
__device__ __forceinline__ uint4 gload_x4(const void* p) {
  uint4 r;
  asm volatile("global_load_dwordx4 %0, %1, off" : "=v"(r) : "v"(p));
  return r;
}

// async global->LDS, 16B per lane (GEMM staging).
__device__ __forceinline__ void gload16(void* lds, const void* g) {
  __builtin_amdgcn_global_load_lds(
      (__attribute__((address_space(1))) void*)(uintptr_t)g,
      (__attribute__((address_space(3))) void*)(unsigned int)(uintptr_t)lds,
      16, 0, 0);
}

// ---------------------------------------------------------------------------
// fp32 -> bf16 elementwise
// ---------------------------------------------------------------------------
__global__ __launch_bounds__(256) void cvt_enc_kernel(
    const float* __restrict__ in, unsigned short* __restrict__ out, long n4)
{
  long i = (long)blockIdx.x * blockDim.x + threadIdx.x;
  const long stride = (long)gridDim.x * blockDim.x;
  for (; i < n4; i += stride) {
    float4 v = ((const float4*)in)[i];
    ushort4 o;
    o.x = f2b(v.x); o.y = f2b(v.y); o.z = f2b(v.z); o.w = f2b(v.w);
    ((ushort4*)out)[i] = o;
  }
}

// ---------------------------------------------------------------------------
// W (K,N) fp32 -> WT (N,K) bf16, 32x32 LDS tile transpose
// ---------------------------------------------------------------------------
__global__ __launch_bounds__(256) void cvt_wt_kernel(
    const float* __restrict__ W, unsigned short* __restrict__ WT, int K, int N)
{
  __shared__ float tile[32][33];
  const int n0 = blockIdx.x * 32, k0 = blockIdx.y * 32;
  const int tx = threadIdx.x, ty = threadIdx.y;  // 32 x 8
#pragma unroll
  for (int i = 0; i < 32; i += 8) {
    int k = k0 + ty + i, n = n0 + tx;
    tile[ty + i][tx] = (k < K && n < N) ? W[(long)k * N + n] : 0.f;
  }
  __syncthreads();
#pragma unroll
  for (int i = 0; i < 32; i += 8) {
    int n = n0 + ty + i, k = k0 + tx;
    if (n < N && k < K) WT[(long)n * K + k] = f2b(tile[tx][ty + i]);
  }
}

// ---------------------------------------------------------------------------
// m97-structure MFMA GEMM: 128x128 tile, BK=32, 256 threads (4 waves, 2x2).
// (unchanged — passing)
// ---------------------------------------------------------------------------
template<int NFULL, int EPI>
__global__ __launch_bounds__(256, 2) void gemm128_kernel(
    const unsigned short* __restrict__ A,
    const unsigned short* __restrict__ WT,
    const float* __restrict__ bias,
    unsigned short* __restrict__ out,
    float2* __restrict__ partials,
    int K)
{
  extern __shared__ char smem[];
  unsigned short* As = (unsigned short*)smem;            // 2 bufs x 4096 shorts
  unsigned short* Bs = (unsigned short*)(smem + 16384);  // 2 bufs x 4096 shorts

  const int tid = threadIdx.x, lane = tid & 63, w = tid >> 6;
  const int wr = w >> 1, wc = w & 1;
  const int cl = lane & 15, g = lane >> 4;
  const int bx = blockIdx.x;
  const long row0 = (long)blockIdx.y * 128;
  const int col0 = bx * 128;

  const int ch0 = w * 64 + lane;
  const int ch1 = 256 + ch0;
  const unsigned short* Ag0 = A + (row0 + (ch0 >> 2)) * K + (ch0 & 3) * 8;
  const unsigned short* Ag1 = A + (row0 + (ch1 >> 2)) * K + (ch1 & 3) * 8;
  const unsigned short* Bg0 = WT + (long)(col0 + (ch0 >> 2)) * K + (ch0 & 3) * 8;
  const unsigned short* Bg1 = WT + (long)(col0 + (ch1 >> 2)) * K + (ch1 & 3) * 8;
  unsigned short* Al0 = As + w * 512;
  unsigned short* Al1 = As + 2048 + w * 512;
  unsigned short* Bl0 = Bs + w * 512;
  unsigned short* Bl1 = Bs + 2048 + w * 512;

#define STAGE(buf, kt)                          \
  do {                                          \
    const int _ko = (kt) * 32;                  \
    gload16(Al0 + (buf) * 4096, Ag0 + _ko);     \
    gload16(Al1 + (buf) * 4096, Ag1 + _ko);     \
    gload16(Bl0 + (buf) * 4096, Bg0 + _ko);     \
    gload16(Bl1 + (buf) * 4096, Bg1 + _ko);     \
  } while (0)

  f32x4 acc[4][4];
#pragma unroll
  for (int mt = 0; mt < 4; ++mt)
#pragma unroll
    for (int nt = 0; nt < 4; ++nt) acc[mt][nt] = (f32x4){0.f, 0.f, 0.f, 0.f};

  const int NKT = K / 32;
  STAGE(0, 0);
  __syncthreads();
  int buf = 0;
  for (int kt = 0; kt < NKT; ++kt) {
    if (kt + 1 < NKT) STAGE(buf ^ 1, kt + 1);
    const unsigned short* Ab = As + buf * 4096;
    const unsigned short* Bb = Bs + buf * 4096;
    bf16x8 af[4], bfr[4];
#pragma unroll
    for (int mt = 0; mt < 4; ++mt)
      af[mt] = *(const bf16x8*)&Ab[(((wr * 64 + mt * 16 + cl) << 2) + g) * 8];
#pragma unroll
    for (int nt = 0; nt < 4; ++nt)
      bfr[nt] = *(const bf16x8*)&Bb[(((wc * 64 + nt * 16 + cl) << 2) + g) * 8];
#pragma unroll
    for (int mt = 0; mt < 4; ++mt)
#pragma unroll
      for (int nt = 0; nt < 4; ++nt)
        acc[mt][nt] = __builtin_amdgcn_mfma_f32_16x16x32_bf16(
            af[mt], bfr[nt], acc[mt][nt], 0, 0, 0);
    __syncthreads();
    buf ^= 1;
  }
#undef STAGE

  float bv[4];
#pragma unroll
  for (int nt = 0; nt < 4; ++nt) bv[nt] = bias[col0 + wc * 64 + nt * 16 + cl];
#pragma unroll
  for (int mt = 0; mt < 4; ++mt)
#pragma unroll
    for (int nt = 0; nt < 4; ++nt)
#pragma unroll
      for (int j = 0; j < 4; ++j) {
        float v = acc[mt][nt][j] + bv[nt];
        if (EPI == 1) v = gelu_exact(v);
        acc[mt][nt][j] = v;
      }

  if (EPI == 2) {
#pragma unroll
    for (int mt = 0; mt < 4; ++mt)
#pragma unroll
      for (int j = 0; j < 4; ++j) {
        float mx = fmaxf(fmaxf(acc[mt][0][j], acc[mt][1][j]),
                         fmaxf(acc[mt][2][j], acc[mt][3][j]));
#pragma unroll
        for (int off = 1; off < 16; off <<= 1)
          mx = fmaxf(mx, __shfl_xor(mx, off));
        float sm = 0.f;
#pragma unroll
        for (int nt = 0; nt < 4; ++nt) sm += expf(acc[mt][nt][j] - mx);
#pragma unroll
        for (int off = 1; off < 16; off <<= 1) sm += __shfl_xor(sm, off);
        if (cl == 0) {
          long m = row0 + wr * 64 + mt * 16 + g * 4 + j;
          partials[m * 16 + bx * 2 + wc] = make_float2(mx, sm);
        }
      }
  }

  unsigned short* Ct = (unsigned short*)smem;  // [128][136]
#pragma unroll
  for (int mt = 0; mt < 4; ++mt)
#pragma unroll
    for (int nt = 0; nt < 4; ++nt)
#pragma unroll
      for (int j = 0; j < 4; ++j)
        Ct[(wr * 64 + mt * 16 + g * 4 + j) * 136 + wc * 64 + nt * 16 + cl] =
            f2b(acc[mt][nt][j]);
  __syncthreads();
  for (int idx = tid; idx < 2048; idx += 256) {
    int r = idx >> 4, ch = idx & 15;
    *(bf16x8*)&out[(row0 + r) * NFULL + col0 + ch * 8] =
        *(const bf16x8*)&Ct[r * 136 + ch * 8];
  }
}

// ---------------------------------------------------------------------------
// LayerNorm in place on bf16, one wave per row
// ---------------------------------------------------------------------------
template<int D>
__global__ __launch_bounds__(256) void ln_bf16_kernel(
    unsigned short* __restrict__ X, const float* __restrict__ g,
    const float* __restrict__ bt, long M)
{
  constexpr int NI = D / 256;
  const int lane = threadIdx.x & 63;
  const int wid = threadIdx.x >> 6;
  const long row = (long)blockIdx.x * 4 + wid;
  if (row >= M) return;

  float v[NI * 4];
  float s = 0.f;
#pragma unroll
  for (int i = 0; i < NI; ++i) {
    ushort4 u = *(const ushort4*)&X[row * D + (i * 64 + lane) * 4];
    v[i * 4 + 0] = b2f(u.x); v[i * 4 + 1] = b2f(u.y);
    v[i * 4 + 2] = b2f(u.z); v[i * 4 + 3] = b2f(u.w);
    s += v[i * 4 + 0] + v[i * 4 + 1] + v[i * 4 + 2] + v[i * 4 + 3];
  }
#pragma unroll
  for (int off = 32; off; off >>= 1) s += __shfl_xor(s, off);
  const float mu = s * (1.0f / D);
  float q = 0.f;
#pragma unroll
  for (int i = 0; i < NI * 4; ++i) { float d = v[i] - mu; q += d * d; }
#pragma unroll
  for (int off = 32; off; off >>= 1) q += __shfl_xor(q, off);
  const float rs = rsqrtf(q * (1.0f / D) + 1e-6f);
#pragma unroll
  for (int i = 0; i < NI; ++i) {
    ushort4 o;
    int c = (i * 64 + lane) * 4;
    o.x = f2b((v[i * 4 + 0] - mu) * rs * g[c + 0] + bt[c + 0]);
    o.y = f2b((v[i * 4 + 1] - mu) * rs * g[c + 1] + bt[c + 1]);
    o.z = f2b((v[i * 4 + 2] - mu) * rs * g[c + 2] + bt[c + 2]);
    o.w = f2b((v[i * 4 + 3] - mu) * rs * g[c + 3] + bt[c + 3]);
    *(ushort4*)&X[row * D + c] = o;
  }
}

// ---------------------------------------------------------------------------
// logz combine + label gather. Stores LINEAR probabilities scaled by 2^10
// as BF16: p'[s] = exp(score[lab] - logz) * 1024, 0 for pad states (s >= S).
// ---------------------------------------------------------------------------
__global__ __launch_bounds__(256) void logz_gather_kernel(
    const unsigned short* __restrict__ scores,  // (M, 1024) bf16
    const float2* __restrict__ partials,        // (M, 16)
    const int* __restrict__ targets,
    unsigned short* __restrict__ lp_ext,        // (B, T, LPROW) bf16
    long Mtot, int T, int B, int L, int S)
{
  const int w = threadIdx.x >> 6, lane = threadIdx.x & 63;
  const long m = (long)blockIdx.x * 4 + w;
  if (m >= Mtot) return;

  float2 pp = partials[m * 16 + (lane & 15)];
  float Mx = pp.x, Sv = pp.y;
#pragma unroll
  for (int off = 1; off < 16; off <<= 1) {
    float Mo = __shfl_xor(Mx, off);
    float So = __shfl_xor(Sv, off);
    float Mn = fmaxf(Mx, Mo);
    Sv = Sv * expf(Mx - Mn) + So * expf(Mo - Mn);
    Mx = Mn;
  }
  const float logz = Mx + logf(Sv);
  const int b = (int)(m % B);
  const int t = (int)(m / B);
  const unsigned short* srow = scores + m * 1024;
  bf16x8 o = {0, 0, 0, 0, 0, 0, 0, 0};
#pragma unroll
  for (int j = 0; j < 5; ++j) {
    int s = lane * 5 + j;
    if (s < S) {
      int lab = (s & 1) ? targets[b * L + (s >> 1)] : 0;
      o[j] = (short)f2b(expf(b2f(srow[lab]) - logz) * 1024.0f);  // p * 2^10
    }
  }
  *(bf16x8*)&lp_ext[((long)b * T + t) * LPROW + lane * 8] = o;
}

// ---------------------------------------------------------------------------
// CTC forward scan, LINEAR DOMAIN: one WAVE per batch element. 16-deep
// register ring of inline-asm global_load_dwordx4 + counted s_waitcnt
// vmcnt(15) + sched_barrier(0) per row (T4 pattern) — the compiler CANNOT
// sink these loads or hoist the uses, so 16 KB/wave stays in flight
// (covers ~900cy HBM BDP at ~80cy/row). Cross-lane via DPP row_shr:1 +
// readlane boundary fix (VALU speed). Exact power-of-2 renorm every 8 rows.
// No LDS, no barriers, no transcendentals in the loop.
// LP is over-allocated by 64KB: tail prefetches past T are harmless.
// ---------------------------------------------------------------------------
#define CTC_DEPTH 16
__global__ __launch_bounds__(64, 1) void ctc_scan_kernel(
    const unsigned short* __restrict__ pr,  // (B, T, LPROW) bf16: prob * 1024
    const int* __restrict__ targets, const int* __restrict__ inlens,
    const int* __restrict__ tlens, float* __restrict__ partial,
    int T, int B, int L, int S)
{
  const int b = blockIdx.x;
  const int lane = threadIdx.x;
  const int s0 = lane * 5;
  const int inlen = inlens[b];
  const int tlen = tlens[b];
  const int send = 2 * tlen;
  const int capT = inlen - 1;
  const bool is16 = (lane == 16), is32 = (lane == 32), is48 = (lane == 48);

  const unsigned short* lpb = pr + (long)b * T * LPROW + lane * 8;

  float skm[5];  // skip multiplier 0/1
#pragma unroll
  for (int j = 0; j < 5; ++j) {
    int s = s0 + j;
    float sk = 0.f;
    if (s < S && (s & 1) && s >= 3) {
      int lab = targets[b * L + (s >> 1)];
      int lab2 = targets[b * L + (s >> 1) - 1];
      sk = ((lab != 0) && (lab != lab2)) ? 1.f : 0.f;
    }
    skm[j] = sk;
  }

  // init alpha' from row 0 (plain load; pad states hold 0 in LP)
  float a[5];
  float abv = 0.f, alv = 0.f;
  int corr = 0, corr_cap = 0;
#pragma unroll
  for (int j = 0; j < 5; ++j) {
    int s = s0 + j;
    a[j] = (s <= 1) ? b2f(lpb[j]) : 0.f;
  }
  if (capT == 0) {
#pragma unroll
    for (int j = 0; j < 5; ++j) {
      int s = s0 + j;
      if (s == send) abv = a[j];
      if (s == send - 1) alv = a[j];
    }
    corr_cap = corr;
  }

  // one DP row from a raw uint4 of 8 bf16 (shift/mask -> f32, 5 VALU ops).
#define CTC_PROCESS(rd, tcur)                                                 \
  do {                                                                        \
    float p0 = __uint_as_float((rd).x << 16);                                 \
    float p1 = __uint_as_float((rd).x & 0xffff0000u);                         \
    float p2 = __uint_as_float((rd).y << 16);                                 \
    float p3 = __uint_as_float((rd).y & 0xffff0000u);                         \
    float p4 = __uint_as_float((rd).z << 16);                                 \
    float r15 = readlane_f(a[4], 15), r31 = readlane_f(a[4], 31),             \
          r47 = readlane_f(a[4], 47);                                         \
    float q15 = readlane_f(a[3], 15), q31 = readlane_f(a[3], 31),             \
          q47 = readlane_f(a[3], 47);                                         \
    float o_m1 = dpp_shr<1>(a[4]);                                            \
    float o_m2 = dpp_shr<1>(a[3]);                                            \
    o_m1 = is16 ? r15 : o_m1; o_m1 = is32 ? r31 : o_m1;                       \
    o_m1 = is48 ? r47 : o_m1;                                                 \
    o_m2 = is16 ? q15 : o_m2; o_m2 = is32 ? q31 : o_m2;                       \
    o_m2 = is48 ? q47 : o_m2;                                                 \
    float na0 = fmaf(skm[0], o_m2, a[0] + o_m1) * p0;                         \
    float na1 = fmaf(skm[1], o_m1, a[1] + a[0]) * p1;                         \
    float na2 = fmaf(skm[2], a[0], a[2] + a[1]) * p2;                         \
    float na3 = fmaf(skm[3], a[1], a[3] + a[2]) * p3;                         \
    float na4 = fmaf(skm[4], a[2], a[4] + a[3]) * p4;                         \
    a[0] = na0; a[1] = na1; a[2] = na2; a[3] = na3; a[4] = na4;               \
    if ((tcur) == capT) {                                                     \
      _Pragma("unroll")                                                       \
      for (int j = 0; j < 5; ++j) {                                           \
        int s = s0 + j;                                                       \
        if (s == send) abv = a[j];                                            \
        if (s == send - 1) alv = a[j];                                        \
      }                                                                       \
      corr_cap = corr;                                                        \
    }                                                                         \
  } while (0)

  // exact power-of-2 wave renorm, VALU-only (DPP prefix-max + readlanes)
#define CTC_RENORM                                                            \
  do {                                                                        \
    float m_ = fmaxf(fmaxf(fmaxf(a[0], a[1]), fmaxf(a[2], a[3])), a[4]);      \
    m_ = fmaxf(m_, dpp_shr<1>(m_));                                           \
    m_ = fmaxf(m_, dpp_shr<2>(m_));                                           \
    m_ = fmaxf(m_, dpp_shr<4>(m_));                                           \
    m_ = fmaxf(m_, dpp_shr<8>(m_));                                           \
    float mx = fmaxf(fmaxf(readlane_f(m_, 15), readlane_f(m_, 31)),           \
                     fmaxf(readlane_f(m_, 47), readlane_f(m_, 63)));          \
    int e;                                                                    \
    (void)frexpf(mx, &e);  /* mx == 0 -> e = 0 -> no-op */                    \
    float sc = ldexpf(1.f, -e);                                               \
    _Pragma("unroll")                                                         \
    for (int j = 0; j < 5; ++j) a[j] *= sc;                                   \
    corr += e;                                                                \
  } while (0)

  // prologue: issue loads for rows 1..CTC_DEPTH (asm: issue order pinned)
  uint4 ring[CTC_DEPTH];
#pragma unroll
  for (int d = 0; d < CTC_DEPTH; ++d)
    ring[d] = gload_x4(lpb + (long)(1 + d) * LPROW);

  const int NCH = (T - 1 + CTC_DEPTH - 1) / CTC_DEPTH;
  int t = 1;
  for (int c = 0; c < NCH; ++c) {
#pragma unroll
    for (int d = 0; d < CTC_DEPTH; ++d) {
      // wait for the oldest load (row t), pin all following ops after it
      asm volatile("s_waitcnt vmcnt(15)" ::: "memory");
      __builtin_amdgcn_sched_barrier(0);
      if (t < T) CTC_PROCESS(ring[d], t);
      // re-issue this slot for row t+DEPTH (slack-protected past T)
      ring[d] = gload_x4(lpb + (long)(t + CTC_DEPTH) * LPROW);
      if ((d & 7) == 7) CTC_RENORM;
      ++t;
    }
  }
  asm volatile("s_waitcnt vmcnt(0)" ::: "memory");

  // reduce the (single-lane-held) captures across the wave (one-time)
#pragma unroll
  for (int off = 32; off; off >>= 1) {
    abv = fmaxf(abv, __shfl_xor(abv, off));
    alv = fmaxf(alv, __shfl_xor(alv, off));
  }
  if (lane == 0) {
    // true log2(alpha) = log2(alpha') + corr_cap - 10*inlen
    float l2 = fast_log2(abv + alv) + (float)corr_cap - 10.0f * (float)inlen;
    float loss = -LN2 * l2;
    if (!(loss <= 1e29f)) loss = 0.f;  // zero_infinity (also catches NaN)
    partial[b] = loss / (float)tlen;
  }
}

__global__ void reduce_kernel(const float* __restrict__ partial,
                              float* __restrict__ out, int B)
{
  int lane = threadIdx.x;
  float v = (lane < B) ? partial[lane] : 0.f;
#pragma unroll
  for (int off = 32; off; off >>= 1) v += __shfl_xor(v, off);
  if (lane == 0) out[0] = v / (float)B;
}

// ---------------------------------------------------------------------------
extern "C" void kernel_launch(void* const* d_in, const int* in_sizes, int n_in,
                              void* d_out, int out_size, void* d_ws, size_t ws_size,
                              hipStream_t stream) {
  const float* enc = (const float*)d_in[0];
  const float* Wp  = (const float*)d_in[1];
  const float* bp  = (const float*)d_in[2];
  const float* Wt  = (const float*)d_in[3];
  const float* btr = (const float*)d_in[4];
  const float* lng = (const float*)d_in[5];
  const float* lnb = (const float*)d_in[6];
  const float* Wd  = (const float*)d_in[7];
  const float* bd  = (const float*)d_in[8];
  const int* tgt   = (const int*)d_in[9];
  const int* inl   = (const int*)d_in[10];
  const int* tll   = (const int*)d_in[11];

  const int D = in_sizes[2];              // 768
  const int V = in_sizes[8];              // 1024
  const int B = in_sizes[10];             // 32
  const int L = in_sizes[9] / B;          // 150
  const long M = (long)in_sizes[0] / D;   // T*B = 64000
  const int T = (int)(M / B);             // 2000
  const int S = 2 * L + 1;                // 301

  char* wsb = (char*)d_ws;
  size_t off = 0;
  auto alloc = [&](size_t bytes) { char* p = wsb + off; off += (bytes + 255) & ~(size_t)255; return p; };
  unsigned short* encb   = (unsigned short*)alloc((size_t)M * D * 2);
  char* x1region         = alloc((size_t)M * V * 2);
  unsigned short* X1b    = (unsigned short*)x1region;   // dead after gemm2
  unsigned short* scores = (unsigned short*)x1region;   // written by gemm3
  unsigned short* X2b    = encb;                        // encb dead after gemm1
  // +64KB slack: ctc tail prefetch reads up to CTC_DEPTH rows past the end
  unsigned short* LP     = (unsigned short*)alloc((size_t)B * T * LPROW * 2 + 65536);
  float2* partials       = (float2*)alloc((size_t)M * 16 * sizeof(float2));
  unsigned short* WpT    = (unsigned short*)alloc((size_t)D * D * 2);
  unsigned short* WtT    = (unsigned short*)alloc((size_t)D * D * 2);
  unsigned short* WdT    = (unsigned short*)alloc((size_t)D * V * 2);
  float* partial         = (float*)alloc(256);

  cvt_wt_kernel<<<dim3(D / 32, D / 32), dim3(32, 8), 0, stream>>>(Wp, WpT, D, D);
  cvt_wt_kernel<<<dim3(D / 32, D / 32), dim3(32, 8), 0, stream>>>(Wt, WtT, D, D);
  cvt_wt_kernel<<<dim3(V / 32, D / 32), dim3(32, 8), 0, stream>>>(Wd, WdT, D, V);
  cvt_enc_kernel<<<2048, 256, 0, stream>>>(enc, encb, (long)M * D / 4);

  const size_t smemg = 34816;
  const dim3 g12(D / 128, (unsigned)(M / 128));   // (6, 500)
  const dim3 g3(V / 128, (unsigned)(M / 128));    // (8, 500)

  gemm128_kernel<768, 0><<<g12, 256, smemg, stream>>>(encb, WpT, bp, X1b, nullptr, D);
  gemm128_kernel<768, 1><<<g12, 256, smemg, stream>>>(X1b, WtT, btr, X2b, nullptr, D);
  ln_bf16_kernel<768><<<(int)(M / 4), 256, 0, stream>>>(X2b, lng, lnb, M);
  gemm128_kernel<1024, 2><<<g3, 256, smemg, stream>>>(X2b, WdT, bd, scores, partials, D);

  logz_gather_kernel<<<(int)(M / 4), 256, 0, stream>>>(
      scores, partials, tgt, LP, M, T, B, L, S);
  ctc_scan_kernel<<<B, 64, 0, stream>>>(LP, tgt, inl, tll, partial, T, B, L, S);
  reduce_kernel<<<1, 64, 0, stream>>>(partial, (float*)d_out, B);
}

// Round 17
// 772.936 us; speedup vs baseline: 1.1104x; 1.0439x over previous
//
#include <hip/hip_runtime.h>
#include <hip/hip_bf16.h>
#include <math.h>
#include <stdint.h>

#define NEGF (-1e30f)
#define LOG2E 1.44269504088896340736f
#define LN2 0.69314718055994530942f

// lp row layout for the CTC scan: 64 lane-groups x 8 bf16 (5 used, 3 pad)
#define LPROW 512

typedef short bf16x8 __attribute__((ext_vector_type(8)));
typedef float f32x4 __attribute__((ext_vector_type(4)));

__device__ __forceinline__ unsigned short f2b(float x) {
  __hip_bfloat16 h = __float2bfloat16(x);
  return *reinterpret_cast<unsigned short*>(&h);
}
__device__ __forceinline__ float b2f(unsigned short u) {
  __hip_bfloat16 h;
  *reinterpret_cast<unsigned short*>(&h) = u;
  return __bfloat162float(h);
}
__device__ __forceinline__ float gelu_exact(float x) {
  return 0.5f * x * (1.0f + erff(x * 0.70710678118654752440f));
}

#if __has_builtin(__builtin_amdgcn_logf)
__device__ __forceinline__ float fast_log2(float x) { return __builtin_amdgcn_logf(x); }
#else
__device__ __forceinline__ float fast_log2(float x) { return log2f(x); }
#endif

// VALU-speed cross-lane helpers (no LDS/ds_bpermute on the critical path)
template<int CTRL>
__device__ __forceinline__ float dpp_shr(float x) {
  // row_shr:N within 16-lane rows; bound_ctrl=1 -> out-of-row reads give 0
  return __int_as_float(__builtin_amdgcn_update_dpp(
      0, __float_as_int(x), 0x110 | CTRL, 0xf, 0xf, true));
}
__device__ __forceinline__ float readlane_f(float x, int l) {
  return __int_as_float(__builtin_amdgcn_readlane(__float_as_int(x), l));
}

// inline-asm 16B global load: issue point is PINNED (asm volatile); result is
// valid only after a matching s_waitcnt vmcnt(N) (also asm volatile).
__device__ __forceinline__ uint4 gload_x4(const void* p) {
  uint4 r;
  asm volatile("global_load_dwordx4 %0, %1, off" : "=v"(r) : "v"(p));
  return r;
}

// async global->LDS, 16B per lane (GEMM staging).
__device__ __forceinline__ void gload16(void* lds, const void* g) {
  __builtin_amdgcn_global_load_lds(
      (__attribute__((address_space(1))) void*)(uintptr_t)g,
      (__attribute__((address_space(3))) void*)(unsigned int)(uintptr_t)lds,
      16, 0, 0);
}

// ---------------------------------------------------------------------------
// fp32 -> bf16 elementwise
// ---------------------------------------------------------------------------
__global__ __launch_bounds__(256) void cvt_enc_kernel(
    const float* __restrict__ in, unsigned short* __restrict__ out, long n4)
{
  long i = (long)blockIdx.x * blockDim.x + threadIdx.x;
  const long stride = (long)gridDim.x * blockDim.x;
  for (; i < n4; i += stride) {
    float4 v = ((const float4*)in)[i];
    ushort4 o;
    o.x = f2b(v.x); o.y = f2b(v.y); o.z = f2b(v.z); o.w = f2b(v.w);
    ((ushort4*)out)[i] = o;
  }
}

// ---------------------------------------------------------------------------
// W (K,N) fp32 -> WT (N,K) bf16, 32x32 LDS tile transpose
// ---------------------------------------------------------------------------
__global__ __launch_bounds__(256) void cvt_wt_kernel(
    const float* __restrict__ W, unsigned short* __restrict__ WT, int K, int N)
{
  __shared__ float tile[32][33];
  const int n0 = blockIdx.x * 32, k0 = blockIdx.y * 32;
  const int tx = threadIdx.x, ty = threadIdx.y;  // 32 x 8
#pragma unroll
  for (int i = 0; i < 32; i += 8) {
    int k = k0 + ty + i, n = n0 + tx;
    tile[ty + i][tx] = (k < K && n < N) ? W[(long)k * N + n] : 0.f;
  }
  __syncthreads();
#pragma unroll
  for (int i = 0; i < 32; i += 8) {
    int n = n0 + ty + i, k = k0 + tx;
    if (n < N && k < K) WT[(long)n * K + k] = f2b(tile[tx][ty + i]);
  }
}

// ---------------------------------------------------------------------------
// m97-structure MFMA GEMM: 128x128 tile, BK=32, 256 threads (4 waves, 2x2).
// 1-D grid + bijective XCD swizzle (T1): the gx blocks sharing an A-row
// panel become XCD-contiguous -> panel L2 locality. nwg % 8 == 0 required.
// ---------------------------------------------------------------------------
template<int NFULL, int EPI>
__global__ __launch_bounds__(256, 2) void gemm128_kernel(
    const unsigned short* __restrict__ A,
    const unsigned short* __restrict__ WT,
    const float* __restrict__ bias,
    unsigned short* __restrict__ out,
    float2* __restrict__ partials,
    int K, int gx, int nwg)
{
  extern __shared__ char smem[];
  unsigned short* As = (unsigned short*)smem;            // 2 bufs x 4096 shorts
  unsigned short* Bs = (unsigned short*)(smem + 16384);  // 2 bufs x 4096 shorts

  const int tid = threadIdx.x, lane = tid & 63, w = tid >> 6;
  const int wr = w >> 1, wc = w & 1;
  const int cl = lane & 15, g = lane >> 4;
  const int bid = blockIdx.x;
  const int wid = (bid & 7) * (nwg >> 3) + (bid >> 3);  // XCD-contiguous chunks
  const int bx = wid % gx;
  const long row0 = (long)(wid / gx) * 128;
  const int col0 = bx * 128;

  const int ch0 = w * 64 + lane;
  const int ch1 = 256 + ch0;
  const unsigned short* Ag0 = A + (row0 + (ch0 >> 2)) * K + (ch0 & 3) * 8;
  const unsigned short* Ag1 = A + (row0 + (ch1 >> 2)) * K + (ch1 & 3) * 8;
  const unsigned short* Bg0 = WT + (long)(col0 + (ch0 >> 2)) * K + (ch0 & 3) * 8;
  const unsigned short* Bg1 = WT + (long)(col0 + (ch1 >> 2)) * K + (ch1 & 3) * 8;
  unsigned short* Al0 = As + w * 512;
  unsigned short* Al1 = As + 2048 + w * 512;
  unsigned short* Bl0 = Bs + w * 512;
  unsigned short* Bl1 = Bs + 2048 + w * 512;

#define STAGE(buf, kt)                          \
  do {                                          \
    const int _ko = (kt) * 32;                  \
    gload16(Al0 + (buf) * 4096, Ag0 + _ko);     \
    gload16(Al1 + (buf) * 4096, Ag1 + _ko);     \
    gload16(Bl0 + (buf) * 4096, Bg0 + _ko);     \
    gload16(Bl1 + (buf) * 4096, Bg1 + _ko);     \
  } while (0)

  f32x4 acc[4][4];
#pragma unroll
  for (int mt = 0; mt < 4; ++mt)
#pragma unroll
    for (int nt = 0; nt < 4; ++nt) acc[mt][nt] = (f32x4){0.f, 0.f, 0.f, 0.f};

  const int NKT = K / 32;
  STAGE(0, 0);
  __syncthreads();
  int buf = 0;
  for (int kt = 0; kt < NKT; ++kt) {
    if (kt + 1 < NKT) STAGE(buf ^ 1, kt + 1);
    const unsigned short* Ab = As + buf * 4096;
    const unsigned short* Bb = Bs + buf * 4096;
    bf16x8 af[4], bfr[4];
#pragma unroll
    for (int mt = 0; mt < 4; ++mt)
      af[mt] = *(const bf16x8*)&Ab[(((wr * 64 + mt * 16 + cl) << 2) + g) * 8];
#pragma unroll
    for (int nt = 0; nt < 4; ++nt)
      bfr[nt] = *(const bf16x8*)&Bb[(((wc * 64 + nt * 16 + cl) << 2) + g) * 8];
#pragma unroll
    for (int mt = 0; mt < 4; ++mt)
#pragma unroll
      for (int nt = 0; nt < 4; ++nt)
        acc[mt][nt] = __builtin_amdgcn_mfma_f32_16x16x32_bf16(
            af[mt], bfr[nt], acc[mt][nt], 0, 0, 0);
    __syncthreads();
    buf ^= 1;
  }
#undef STAGE

  float bv[4];
#pragma unroll
  for (int nt = 0; nt < 4; ++nt) bv[nt] = bias[col0 + wc * 64 + nt * 16 + cl];
#pragma unroll
  for (int mt = 0; mt < 4; ++mt)
#pragma unroll
    for (int nt = 0; nt < 4; ++nt)
#pragma unroll
      for (int j = 0; j < 4; ++j) {
        float v = acc[mt][nt][j] + bv[nt];
        if (EPI == 1) v = gelu_exact(v);
        acc[mt][nt][j] = v;
      }

  if (EPI == 2) {
#pragma unroll
    for (int mt = 0; mt < 4; ++mt)
#pragma unroll
      for (int j = 0; j < 4; ++j) {
        float mx = fmaxf(fmaxf(acc[mt][0][j], acc[mt][1][j]),
                         fmaxf(acc[mt][2][j], acc[mt][3][j]));
#pragma unroll
        for (int off = 1; off < 16; off <<= 1)
          mx = fmaxf(mx, __shfl_xor(mx, off));
        float sm = 0.f;
#pragma unroll
        for (int nt = 0; nt < 4; ++nt) sm += expf(acc[mt][nt][j] - mx);
#pragma unroll
        for (int off = 1; off < 16; off <<= 1) sm += __shfl_xor(sm, off);
        if (cl == 0) {
          long m = row0 + wr * 64 + mt * 16 + g * 4 + j;
          partials[m * 16 + bx * 2 + wc] = make_float2(mx, sm);
        }
      }
  }

  unsigned short* Ct = (unsigned short*)smem;  // [128][136]
#pragma unroll
  for (int mt = 0; mt < 4; ++mt)
#pragma unroll
    for (int nt = 0; nt < 4; ++nt)
#pragma unroll
      for (int j = 0; j < 4; ++j)
        Ct[(wr * 64 + mt * 16 + g * 4 + j) * 136 + wc * 64 + nt * 16 + cl] =
            f2b(acc[mt][nt][j]);
  __syncthreads();
  for (int idx = tid; idx < 2048; idx += 256) {
    int r = idx >> 4, ch = idx & 15;
    *(bf16x8*)&out[(row0 + r) * NFULL + col0 + ch * 8] =
        *(const bf16x8*)&Ct[r * 136 + ch * 8];
  }
}

// ---------------------------------------------------------------------------
// LayerNorm in place on bf16, one wave per row
// ---------------------------------------------------------------------------
template<int D>
__global__ __launch_bounds__(256) void ln_bf16_kernel(
    unsigned short* __restrict__ X, const float* __restrict__ g,
    const float* __restrict__ bt, long M)
{
  constexpr int NI = D / 256;
  const int lane = threadIdx.x & 63;
  const int wid = threadIdx.x >> 6;
  const long row = (long)blockIdx.x * 4 + wid;
  if (row >= M) return;

  float v[NI * 4];
  float s = 0.f;
#pragma unroll
  for (int i = 0; i < NI; ++i) {
    ushort4 u = *(const ushort4*)&X[row * D + (i * 64 + lane) * 4];
    v[i * 4 + 0] = b2f(u.x); v[i * 4 + 1] = b2f(u.y);
    v[i * 4 + 2] = b2f(u.z); v[i * 4 + 3] = b2f(u.w);
    s += v[i * 4 + 0] + v[i * 4 + 1] + v[i * 4 + 2] + v[i * 4 + 3];
  }
#pragma unroll
  for (int off = 32; off; off >>= 1) s += __shfl_xor(s, off);
  const float mu = s * (1.0f / D);
  float q = 0.f;
#pragma unroll
  for (int i = 0; i < NI * 4; ++i) { float d = v[i] - mu; q += d * d; }
#pragma unroll
  for (int off = 32; off; off >>= 1) q += __shfl_xor(q, off);
  const float rs = rsqrtf(q * (1.0f / D) + 1e-6f);
#pragma unroll
  for (int i = 0; i < NI; ++i) {
    ushort4 o;
    int c = (i * 64 + lane) * 4;
    o.x = f2b((v[i * 4 + 0] - mu) * rs * g[c + 0] + bt[c + 0]);
    o.y = f2b((v[i * 4 + 1] - mu) * rs * g[c + 1] + bt[c + 1]);
    o.z = f2b((v[i * 4 + 2] - mu) * rs * g[c + 2] + bt[c + 2]);
    o.w = f2b((v[i * 4 + 3] - mu) * rs * g[c + 3] + bt[c + 3]);
    *(ushort4*)&X[row * D + c] = o;
  }
}

// ---------------------------------------------------------------------------
// logz combine + label gather. Stores LINEAR probabilities scaled by 2^10
// as BF16: p'[s] = exp(score[lab] - logz) * 1024, 0 for pad states (s >= S).
// ---------------------------------------------------------------------------
__global__ __launch_bounds__(256) void logz_gather_kernel(
    const unsigned short* __restrict__ scores,  // (M, 1024) bf16
    const float2* __restrict__ partials,        // (M, 16)
    const int* __restrict__ targets,
    unsigned short* __restrict__ lp_ext,        // (B, T, LPROW) bf16
    long Mtot, int T, int B, int L, int S)
{
  const int w = threadIdx.x >> 6, lane = threadIdx.x & 63;
  const long m = (long)blockIdx.x * 4 + w;
  if (m >= Mtot) return;

  float2 pp = partials[m * 16 + (lane & 15)];
  float Mx = pp.x, Sv = pp.y;
#pragma unroll
  for (int off = 1; off < 16; off <<= 1) {
    float Mo = __shfl_xor(Mx, off);
    float So = __shfl_xor(Sv, off);
    float Mn = fmaxf(Mx, Mo);
    Sv = Sv * expf(Mx - Mn) + So * expf(Mo - Mn);
    Mx = Mn;
  }
  const float logz = Mx + logf(Sv);
  const int b = (int)(m % B);
  const int t = (int)(m / B);
  const unsigned short* srow = scores + m * 1024;
  bf16x8 o = {0, 0, 0, 0, 0, 0, 0, 0};
#pragma unroll
  for (int j = 0; j < 5; ++j) {
    int s = lane * 5 + j;
    if (s < S) {
      int lab = (s & 1) ? targets[b * L + (s >> 1)] : 0;
      o[j] = (short)f2b(expf(b2f(srow[lab]) - logz) * 1024.0f);  // p * 2^10
    }
  }
  *(bf16x8*)&lp_ext[((long)b * T + t) * LPROW + lane * 8] = o;
}

// ---------------------------------------------------------------------------
// CTC forward scan, LINEAR DOMAIN: one WAVE per batch element. 8-deep
// pipeline of NAMED uint4 registers (g0..g7 — no array, no scratch; rule
// #20) loaded via inline-asm global_load_dwordx4; each row consumes after
// s_waitcnt vmcnt(7) + sched_barrier(0) and re-issues its slot. Cross-lane
// via DPP row_shr:1 + readlane boundary fix. Exact power-of-2 renorm every
// 8 rows. No LDS, no barriers, no transcendentals in the loop.
// LP is over-allocated by 64KB: tail prefetch past T is harmless.
// ---------------------------------------------------------------------------
__global__ __launch_bounds__(64, 1) void ctc_scan_kernel(
    const unsigned short* __restrict__ pr,  // (B, T, LPROW) bf16: prob * 1024
    const int* __restrict__ targets, const int* __restrict__ inlens,
    const int* __restrict__ tlens, float* __restrict__ partial,
    int T, int B, int L, int S)
{
  const int b = blockIdx.x;
  const int lane = threadIdx.x;
  const int s0 = lane * 5;
  const int inlen = inlens[b];
  const int tlen = tlens[b];
  const int send = 2 * tlen;
  const int capT = inlen - 1;
  const bool is16 = (lane == 16), is32 = (lane == 32), is48 = (lane == 48);

  const unsigned short* lpb = pr + (long)b * T * LPROW + lane * 8;

  float skm[5];  // skip multiplier 0/1
#pragma unroll
  for (int j = 0; j < 5; ++j) {
    int s = s0 + j;
    float sk = 0.f;
    if (s < S && (s & 1) && s >= 3) {
      int lab = targets[b * L + (s >> 1)];
      int lab2 = targets[b * L + (s >> 1) - 1];
      sk = ((lab != 0) && (lab != lab2)) ? 1.f : 0.f;
    }
    skm[j] = sk;
  }

  // init alpha' from row 0 (plain load; pad states hold 0 in LP)
  float a[5];
  float abv = 0.f, alv = 0.f;
  int corr = 0, corr_cap = 0;
#pragma unroll
  for (int j = 0; j < 5; ++j) {
    int s = s0 + j;
    a[j] = (s <= 1) ? b2f(lpb[j]) : 0.f;
  }
  if (capT == 0) {
#pragma unroll
    for (int j = 0; j < 5; ++j) {
      int s = s0 + j;
      if (s == send) abv = a[j];
      if (s == send - 1) alv = a[j];
    }
    corr_cap = corr;
  }

#define CTC_WAIT                                          \
  do {                                                    \
    asm volatile("s_waitcnt vmcnt(7)" ::: "memory");      \
    __builtin_amdgcn_sched_barrier(0);                    \
  } while (0)

  // one DP row from a raw uint4 of 8 bf16 (shift/mask -> f32).
#define CTC_PROCESS(rd, tcur)                                                 \
  do {                                                                        \
    float p0 = __uint_as_float((rd).x << 16);                                 \
    float p1 = __uint_as_float((rd).x & 0xffff0000u);                         \
    float p2 = __uint_as_float((rd).y << 16);                                 \
    float p3 = __uint_as_float((rd).y & 0xffff0000u);                         \
    float p4 = __uint_as_float((rd).z << 16);                                 \
    float r15 = readlane_f(a[4], 15), r31 = readlane_f(a[4], 31),             \
          r47 = readlane_f(a[4], 47);                                         \
    float q15 = readlane_f(a[3], 15), q31 = readlane_f(a[3], 31),             \
          q47 = readlane_f(a[3], 47);                                         \
    float o_m1 = dpp_shr<1>(a[4]);                                            \
    float o_m2 = dpp_shr<1>(a[3]);                                            \
    o_m1 = is16 ? r15 : o_m1; o_m1 = is32 ? r31 : o_m1;                       \
    o_m1 = is48 ? r47 : o_m1;                                                 \
    o_m2 = is16 ? q15 : o_m2; o_m2 = is32 ? q31 : o_m2;                       \
    o_m2 = is48 ? q47 : o_m2;                                                 \
    float na0 = fmaf(skm[0], o_m2, a[0] + o_m1) * p0;                         \
    float na1 = fmaf(skm[1], o_m1, a[1] + a[0]) * p1;                         \
    float na2 = fmaf(skm[2], a[0], a[2] + a[1]) * p2;                         \
    float na3 = fmaf(skm[3], a[1], a[3] + a[2]) * p3;                         \
    float na4 = fmaf(skm[4], a[2], a[4] + a[3]) * p4;                         \
    a[0] = na0; a[1] = na1; a[2] = na2; a[3] = na3; a[4] = na4;               \
    if ((tcur) == capT) {                                                     \
      _Pragma("unroll")                                                       \
      for (int j = 0; j < 5; ++j) {                                           \
        int s = s0 + j;                                                       \
        if (s == send) abv = a[j];                                            \
        if (s == send - 1) alv = a[j];                                        \
      }                                                                       \
      corr_cap = corr;                                                        \
    }                                                                         \
  } while (0)

  // exact power-of-2 wave renorm, VALU-only (DPP prefix-max + readlanes)
#define CTC_RENORM                                                            \
  do {                                                                        \
    float m_ = fmaxf(fmaxf(fmaxf(a[0], a[1]), fmaxf(a[2], a[3])), a[4]);      \
    m_ = fmaxf(m_, dpp_shr<1>(m_));                                           \
    m_ = fmaxf(m_, dpp_shr<2>(m_));                                           \
    m_ = fmaxf(m_, dpp_shr<4>(m_));                                           \
    m_ = fmaxf(m_, dpp_shr<8>(m_));                                           \
    float mx = fmaxf(fmaxf(readlane_f(m_, 15), readlane_f(m_, 31)),           \
                     fmaxf(readlane_f(m_, 47), readlane_f(m_, 63)));          \
    int e;                                                                    \
    (void)frexpf(mx, &e);  /* mx == 0 -> e = 0 -> no-op */                    \
    float sc = ldexpf(1.f, -e);                                               \
    _Pragma("unroll")                                                         \
    for (int j = 0; j < 5; ++j) a[j] *= sc;                                   \
    corr += e;                                                                \
  } while (0)

// consume slot gN (row t), then re-issue it for row t+8
#define CTC_STEP(gN)                                          \
  do {                                                        \
    CTC_WAIT;                                                 \
    if (t < T) CTC_PROCESS(gN, t);                            \
    gN = gload_x4(lpb + (long)(t + 8) * LPROW);               \
    ++t;                                                      \
  } while (0)

  // prologue: 8 named slots, rows 1..8 (issue order pinned by asm volatile)
  uint4 g0 = gload_x4(lpb + (long)1 * LPROW);
  uint4 g1 = gload_x4(lpb + (long)2 * LPROW);
  uint4 g2 = gload_x4(lpb + (long)3 * LPROW);
  uint4 g3 = gload_x4(lpb + (long)4 * LPROW);
  uint4 g4 = gload_x4(lpb + (long)5 * LPROW);
  uint4 g5 = gload_x4(lpb + (long)6 * LPROW);
  uint4 g6 = gload_x4(lpb + (long)7 * LPROW);
  uint4 g7 = gload_x4(lpb + (long)8 * LPROW);

  const int NCH = (T - 1 + 7) / 8;
  int t = 1;
  for (int c = 0; c < NCH; ++c) {
    CTC_STEP(g0);
    CTC_STEP(g1);
    CTC_STEP(g2);
    CTC_STEP(g3);
    CTC_STEP(g4);
    CTC_STEP(g5);
    CTC_STEP(g6);
    CTC_STEP(g7);
    CTC_RENORM;
  }
  asm volatile("s_waitcnt vmcnt(0)" ::: "memory");

  // reduce the (single-lane-held) captures across the wave (one-time)
#pragma unroll
  for (int off = 32; off; off >>= 1) {
    abv = fmaxf(abv, __shfl_xor(abv, off));
    alv = fmaxf(alv, __shfl_xor(alv, off));
  }
  if (lane == 0) {
    // true log2(alpha) = log2(alpha') + corr_cap - 10*inlen
    float l2 = fast_log2(abv + alv) + (float)corr_cap - 10.0f * (float)inlen;
    float loss = -LN2 * l2;
    if (!(loss <= 1e29f)) loss = 0.f;  // zero_infinity (also catches NaN)
    partial[b] = loss / (float)tlen;
  }
}

__global__ void reduce_kernel(const float* __restrict__ partial,
                              float* __restrict__ out, int B)
{
  int lane = threadIdx.x;
  float v = (lane < B) ? partial[lane] : 0.f;
#pragma unroll
  for (int off = 32; off; off >>= 1) v += __shfl_xor(v, off);
  if (lane == 0) out[0] = v / (float)B;
}

// ---------------------------------------------------------------------------
extern "C" void kernel_launch(void* const* d_in, const int* in_sizes, int n_in,
                              void* d_out, int out_size, void* d_ws, size_t ws_size,
                              hipStream_t stream) {
  const float* enc = (const float*)d_in[0];
  const float* Wp  = (const float*)d_in[1];
  const float* bp  = (const float*)d_in[2];
  const float* Wt  = (const float*)d_in[3];
  const float* btr = (const float*)d_in[4];
  const float* lng = (const float*)d_in[5];
  const float* lnb = (const float*)d_in[6];
  const float* Wd  = (const float*)d_in[7];
  const float* bd  = (const float*)d_in[8];
  const int* tgt   = (const int*)d_in[9];
  const int* inl   = (const int*)d_in[10];
  const int* tll   = (const int*)d_in[11];

  const int D = in_sizes[2];              // 768
  const int V = in_sizes[8];              // 1024
  const int B = in_sizes[10];             // 32
  const int L = in_sizes[9] / B;          // 150
  const long M = (long)in_sizes[0] / D;   // T*B = 64000
  const int T = (int)(M / B);             // 2000
  const int S = 2 * L + 1;                // 301

  char* wsb = (char*)d_ws;
  size_t off = 0;
  auto alloc = [&](size_t bytes) { char* p = wsb + off; off += (bytes + 255) & ~(size_t)255; return p; };
  unsigned short* encb   = (unsigned short*)alloc((size_t)M * D * 2);
  char* x1region         = alloc((size_t)M * V * 2);
  unsigned short* X1b    = (unsigned short*)x1region;   // dead after gemm2
  unsigned short* scores = (unsigned short*)x1region;   // written by gemm3
  unsigned short* X2b    = encb;                        // encb dead after gemm1
  // +64KB slack: ctc tail prefetch reads up to 8 rows past the end
  unsigned short* LP     = (unsigned short*)alloc((size_t)B * T * LPROW * 2 + 65536);
  float2* partials       = (float2*)alloc((size_t)M * 16 * sizeof(float2));
  unsigned short* WpT    = (unsigned short*)alloc((size_t)D * D * 2);
  unsigned short* WtT    = (unsigned short*)alloc((size_t)D * D * 2);
  unsigned short* WdT    = (unsigned short*)alloc((size_t)D * V * 2);
  float* partial         = (float*)alloc(256);

  cvt_wt_kernel<<<dim3(D / 32, D / 32), dim3(32, 8), 0, stream>>>(Wp, WpT, D, D);
  cvt_wt_kernel<<<dim3(D / 32, D / 32), dim3(32, 8), 0, stream>>>(Wt, WtT, D, D);
  cvt_wt_kernel<<<dim3(V / 32, D / 32), dim3(32, 8), 0, stream>>>(Wd, WdT, D, V);
  cvt_enc_kernel<<<2048, 256, 0, stream>>>(enc, encb, (long)M * D / 4);

  const size_t smemg = 34816;
  const int gx12 = D / 128, nwg12 = gx12 * (int)(M / 128);  // 6*500 = 3000
  const int gx3 = V / 128, nwg3 = gx3 * (int)(M / 128);     // 8*500 = 4000

  gemm128_kernel<768, 0><<<nwg12, 256, smemg, stream>>>(
      encb, WpT, bp, X1b, nullptr, D, gx12, nwg12);
  gemm128_kernel<768, 1><<<nwg12, 256, smemg, stream>>>(
      X1b, WtT, btr, X2b, nullptr, D, gx12, nwg12);
  ln_bf16_kernel<768><<<(int)(M / 4), 256, 0, stream>>>(X2b, lng, lnb, M);
  gemm128_kernel<1024, 2><<<nwg3, 256, smemg, stream>>>(
      X2b, WdT, bd, scores, partials, D, gx3, nwg3);

  logz_gather_kernel<<<(int)(M / 4), 256, 0, stream>>>(
      scores, partials, tgt, LP, M, T, B, L, S);
  ctc_scan_kernel<<<B, 64, 0, stream>>>(LP, tgt, inl, tll, partial, T, B, L, S);
  reduce_kernel<<<1, 64, 0, stream>>>(partial, (float*)d_out, B);
}

// Round 18
// 762.126 us; speedup vs baseline: 1.1261x; 1.0142x over previous
//
#include <hip/hip_runtime.h>
#include <hip/hip_bf16.h>
#include <math.h>
#include <stdint.h>

#define NEGF (-1e30f)
#define LOG2E 1.44269504088896340736f
#define LN2 0.69314718055994530942f

// lp row layout for the CTC scan: 64 lane-groups x 8 bf16 (5 used, 3 pad)
#define LPROW 512

typedef short bf16x8 __attribute__((ext_vector_type(8)));
typedef float f32x4 __attribute__((ext_vector_type(4)));
typedef unsigned int u32x4 __attribute__((ext_vector_type(4)));  // native 4-VGPR tuple

__device__ __forceinline__ unsigned short f2b(float x) {
  __hip_bfloat16 h = __float2bfloat16(x);
  return *reinterpret_cast<unsigned short*>(&h);
}
__device__ __forceinline__ float b2f(unsigned short u) {
  __hip_bfloat16 h;
  *reinterpret_cast<unsigned short*>(&h) = u;
  return __bfloat162float(h);
}
__device__ __forceinline__ float gelu_exact(float x) {
  return 0.5f * x * (1.0f + erff(x * 0.70710678118654752440f));
}

#if __has_builtin(__builtin_amdgcn_logf)
__device__ __forceinline__ float fast_log2(float x) { return __builtin_amdgcn_logf(x); }
#else
__device__ __forceinline__ float fast_log2(float x) { return log2f(x); }
#endif

// VALU-speed cross-lane helpers (no LDS/ds_bpermute on the critical path)
template<int CTRL>
__device__ __forceinline__ float dpp_shr(float x) {
  // row_shr:N within 16-lane rows; bound_ctrl=1 -> out-of-row reads give 0
  return __int_as_float(__builtin_amdgcn_update_dpp(
      0, __float_as_int(x), 0x110 | CTRL, 0xf, 0xf, true));
}
__device__ __forceinline__ float readlane_f(float x, int l) {
  return __int_as_float(__builtin_amdgcn_readlane(__float_as_int(x), l));
}

// inline-asm 16B global load into a NATIVE ext_vector (4-VGPR tuple — no
// struct round-trip through scratch). Issue point pinned by asm volatile;
// result valid only after a matching s_waitcnt vmcnt(N).
__device__ __forceinline__ u32x4 gload_x4(const void* p) {
  u32x4 r;
  asm volatile("global_load_dwordx4 %0, %1, off" : "=v"(r) : "v"(p));
  return r;
}

// async global->LDS, 16B per lane (GEMM staging).
__device__ __forceinline__ void gload16(void* lds, const void* g) {
  __builtin_amdgcn_global_load_lds(
      (__attribute__((address_space(1))) void*)(uintptr_t)g,
      (__attribute__((address_space(3))) void*)(unsigned int)(uintptr_t)lds,
      16, 0, 0);
}

// ---------------------------------------------------------------------------
// fp32 -> bf16 elementwise
// ---------------------------------------------------------------------------
__global__ __launch_bounds__(256) void cvt_enc_kernel(
    const float* __restrict__ in, unsigned short* __restrict__ out, long n4)
{
  long i = (long)blockIdx.x * blockDim.x + threadIdx.x;
  const long stride = (long)gridDim.x * blockDim.x;
  for (; i < n4; i += stride) {
    float4 v = ((const float4*)in)[i];
    ushort4 o;
    o.x = f2b(v.x); o.y = f2b(v.y); o.z = f2b(v.z); o.w = f2b(v.w);
    ((ushort4*)out)[i] = o;
  }
}

// ---------------------------------------------------------------------------
// W (K,N) fp32 -> WT (N,K) bf16, 32x32 LDS tile transpose
// ---------------------------------------------------------------------------
__global__ __launch_bounds__(256) void cvt_wt_kernel(
    const float* __restrict__ W, unsigned short* __restrict__ WT, int K, int N)
{
  __shared__ float tile[32][33];
  const int n0 = blockIdx.x * 32, k0 = blockIdx.y * 32;
  const int tx = threadIdx.x, ty = threadIdx.y;  // 32 x 8
#pragma unroll
  for (int i = 0; i < 32; i += 8) {
    int k = k0 + ty + i, n = n0 + tx;
    tile[ty + i][tx] = (k < K && n < N) ? W[(long)k * N + n] : 0.f;
  }
  __syncthreads();
#pragma unroll
  for (int i = 0; i < 32; i += 8) {
    int n = n0 + ty + i, k = k0 + tx;
    if (n < N && k < K) WT[(long)n * K + k] = f2b(tile[tx][ty + i]);
  }
}

// ---------------------------------------------------------------------------
// m97-structure MFMA GEMM: 128x128 tile, BK=32, 256 threads (4 waves, 2x2).
// 1-D grid + bijective XCD swizzle (T1). nwg % 8 == 0 required.
// ---------------------------------------------------------------------------
template<int NFULL, int EPI>
__global__ __launch_bounds__(256, 2) void gemm128_kernel(
    const unsigned short* __restrict__ A,
    const unsigned short* __restrict__ WT,
    const float* __restrict__ bias,
    unsigned short* __restrict__ out,
    float2* __restrict__ partials,
    int K, int gx, int nwg)
{
  extern __shared__ char smem[];
  unsigned short* As = (unsigned short*)smem;            // 2 bufs x 4096 shorts
  unsigned short* Bs = (unsigned short*)(smem + 16384);  // 2 bufs x 4096 shorts

  const int tid = threadIdx.x, lane = tid & 63, w = tid >> 6;
  const int wr = w >> 1, wc = w & 1;
  const int cl = lane & 15, g = lane >> 4;
  const int bid = blockIdx.x;
  const int wid = (bid & 7) * (nwg >> 3) + (bid >> 3);  // XCD-contiguous chunks
  const int bx = wid % gx;
  const long row0 = (long)(wid / gx) * 128;
  const int col0 = bx * 128;

  const int ch0 = w * 64 + lane;
  const int ch1 = 256 + ch0;
  const unsigned short* Ag0 = A + (row0 + (ch0 >> 2)) * K + (ch0 & 3) * 8;
  const unsigned short* Ag1 = A + (row0 + (ch1 >> 2)) * K + (ch1 & 3) * 8;
  const unsigned short* Bg0 = WT + (long)(col0 + (ch0 >> 2)) * K + (ch0 & 3) * 8;
  const unsigned short* Bg1 = WT + (long)(col0 + (ch1 >> 2)) * K + (ch1 & 3) * 8;
  unsigned short* Al0 = As + w * 512;
  unsigned short* Al1 = As + 2048 + w * 512;
  unsigned short* Bl0 = Bs + w * 512;
  unsigned short* Bl1 = Bs + 2048 + w * 512;

#define STAGE(buf, kt)                          \
  do {                                          \
    const int _ko = (kt) * 32;                  \
    gload16(Al0 + (buf) * 4096, Ag0 + _ko);     \
    gload16(Al1 + (buf) * 4096, Ag1 + _ko);     \
    gload16(Bl0 + (buf) * 4096, Bg0 + _ko);     \
    gload16(Bl1 + (buf) * 4096, Bg1 + _ko);     \
  } while (0)

  f32x4 acc[4][4];
#pragma unroll
  for (int mt = 0; mt < 4; ++mt)
#pragma unroll
    for (int nt = 0; nt < 4; ++nt) acc[mt][nt] = (f32x4){0.f, 0.f, 0.f, 0.f};

  const int NKT = K / 32;
  STAGE(0, 0);
  __syncthreads();
  int buf = 0;
  for (int kt = 0; kt < NKT; ++kt) {
    if (kt + 1 < NKT) STAGE(buf ^ 1, kt + 1);
    const unsigned short* Ab = As + buf * 4096;
    const unsigned short* Bb = Bs + buf * 4096;
    bf16x8 af[4], bfr[4];
#pragma unroll
    for (int mt = 0; mt < 4; ++mt)
      af[mt] = *(const bf16x8*)&Ab[(((wr * 64 + mt * 16 + cl) << 2) + g) * 8];
#pragma unroll
    for (int nt = 0; nt < 4; ++nt)
      bfr[nt] = *(const bf16x8*)&Bb[(((wc * 64 + nt * 16 + cl) << 2) + g) * 8];
#pragma unroll
    for (int mt = 0; mt < 4; ++mt)
#pragma unroll
      for (int nt = 0; nt < 4; ++nt)
        acc[mt][nt] = __builtin_amdgcn_mfma_f32_16x16x32_bf16(
            af[mt], bfr[nt], acc[mt][nt], 0, 0, 0);
    __syncthreads();
    buf ^= 1;
  }
#undef STAGE

  float bv[4];
#pragma unroll
  for (int nt = 0; nt < 4; ++nt) bv[nt] = bias[col0 + wc * 64 + nt * 16 + cl];
#pragma unroll
  for (int mt = 0; mt < 4; ++mt)
#pragma unroll
    for (int nt = 0; nt < 4; ++nt)
#pragma unroll
      for (int j = 0; j < 4; ++j) {
        float v = acc[mt][nt][j] + bv[nt];
        if (EPI == 1) v = gelu_exact(v);
        acc[mt][nt][j] = v;
      }

  if (EPI == 2) {
#pragma unroll
    for (int mt = 0; mt < 4; ++mt)
#pragma unroll
      for (int j = 0; j < 4; ++j) {
        float mx = fmaxf(fmaxf(acc[mt][0][j], acc[mt][1][j]),
                         fmaxf(acc[mt][2][j], acc[mt][3][j]));
#pragma unroll
        for (int off = 1; off < 16; off <<= 1)
          mx = fmaxf(mx, __shfl_xor(mx, off));
        float sm = 0.f;
#pragma unroll
        for (int nt = 0; nt < 4; ++nt) sm += expf(acc[mt][nt][j] - mx);
#pragma unroll
        for (int off = 1; off < 16; off <<= 1) sm += __shfl_xor(sm, off);
        if (cl == 0) {
          long m = row0 + wr * 64 + mt * 16 + g * 4 + j;
          partials[m * 16 + bx * 2 + wc] = make_float2(mx, sm);
        }
      }
  }

  unsigned short* Ct = (unsigned short*)smem;  // [128][136]
#pragma unroll
  for (int mt = 0; mt < 4; ++mt)
#pragma unroll
    for (int nt = 0; nt < 4; ++nt)
#pragma unroll
      for (int j = 0; j < 4; ++j)
        Ct[(wr * 64 + mt * 16 + g * 4 + j) * 136 + wc * 64 + nt * 16 + cl] =
            f2b(acc[mt][nt][j]);
  __syncthreads();
  for (int idx = tid; idx < 2048; idx += 256) {
    int r = idx >> 4, ch = idx & 15;
    *(bf16x8*)&out[(row0 + r) * NFULL + col0 + ch * 8] =
        *(const bf16x8*)&Ct[r * 136 + ch * 8];
  }
}

// ---------------------------------------------------------------------------
// LayerNorm in place on bf16, one wave per row
// ---------------------------------------------------------------------------
template<int D>
__global__ __launch_bounds__(256) void ln_bf16_kernel(
    unsigned short* __restrict__ X, const float* __restrict__ g,
    const float* __restrict__ bt, long M)
{
  constexpr int NI = D / 256;
  const int lane = threadIdx.x & 63;
  const int wid = threadIdx.x >> 6;
  const long row = (long)blockIdx.x * 4 + wid;
  if (row >= M) return;

  float v[NI * 4];
  float s = 0.f;
#pragma unroll
  for (int i = 0; i < NI; ++i) {
    ushort4 u = *(const ushort4*)&X[row * D + (i * 64 + lane) * 4];
    v[i * 4 + 0] = b2f(u.x); v[i * 4 + 1] = b2f(u.y);
    v[i * 4 + 2] = b2f(u.z); v[i * 4 + 3] = b2f(u.w);
    s += v[i * 4 + 0] + v[i * 4 + 1] + v[i * 4 + 2] + v[i * 4 + 3];
  }
#pragma unroll
  for (int off = 32; off; off >>= 1) s += __shfl_xor(s, off);
  const float mu = s * (1.0f / D);
  float q = 0.f;
#pragma unroll
  for (int i = 0; i < NI * 4; ++i) { float d = v[i] - mu; q += d * d; }
#pragma unroll
  for (int off = 32; off; off >>= 1) q += __shfl_xor(q, off);
  const float rs = rsqrtf(q * (1.0f / D) + 1e-6f);
#pragma unroll
  for (int i = 0; i < NI; ++i) {
    ushort4 o;
    int c = (i * 64 + lane) * 4;
    o.x = f2b((v[i * 4 + 0] - mu) * rs * g[c + 0] + bt[c + 0]);
    o.y = f2b((v[i * 4 + 1] - mu) * rs * g[c + 1] + bt[c + 1]);
    o.z = f2b((v[i * 4 + 2] - mu) * rs * g[c + 2] + bt[c + 2]);
    o.w = f2b((v[i * 4 + 3] - mu) * rs * g[c + 3] + bt[c + 3]);
    *(ushort4*)&X[row * D + c] = o;
  }
}

// ---------------------------------------------------------------------------
// logz combine + label gather. Stores LINEAR probabilities scaled by 2^10
// as BF16: p'[s] = exp(score[lab] - logz) * 1024, 0 for pad states (s >= S).
// ---------------------------------------------------------------------------
__global__ __launch_bounds__(256) void logz_gather_kernel(
    const unsigned short* __restrict__ scores,  // (M, 1024) bf16
    const float2* __restrict__ partials,        // (M, 16)
    const int* __restrict__ targets,
    unsigned short* __restrict__ lp_ext,        // (B, T, LPROW) bf16
    long Mtot, int T, int B, int L, int S)
{
  const int w = threadIdx.x >> 6, lane = threadIdx.x & 63;
  const long m = (long)blockIdx.x * 4 + w;
  if (m >= Mtot) return;

  float2 pp = partials[m * 16 + (lane & 15)];
  float Mx = pp.x, Sv = pp.y;
#pragma unroll
  for (int off = 1; off < 16; off <<= 1) {
    float Mo = __shfl_xor(Mx, off);
    float So = __shfl_xor(Sv, off);
    float Mn = fmaxf(Mx, Mo);
    Sv = Sv * expf(Mx - Mn) + So * expf(Mo - Mn);
    Mx = Mn;
  }
  const float logz = Mx + logf(Sv);
  const int b = (int)(m % B);
  const int t = (int)(m / B);
  const unsigned short* srow = scores + m * 1024;
  bf16x8 o = {0, 0, 0, 0, 0, 0, 0, 0};
#pragma unroll
  for (int j = 0; j < 5; ++j) {
    int s = lane * 5 + j;
    if (s < S) {
      int lab = (s & 1) ? targets[b * L + (s >> 1)] : 0;
      o[j] = (short)f2b(expf(b2f(srow[lab]) - logz) * 1024.0f);  // p * 2^10
    }
  }
  *(bf16x8*)&lp_ext[((long)b * T + t) * LPROW + lane * 8] = o;
}

// ---------------------------------------------------------------------------
// CTC forward scan, LINEAR DOMAIN: one WAVE per batch element. 8-deep
// pipeline of NAMED ext_vector u32x4 registers (native 4-VGPR tuples — no
// struct->scratch round-trip) loaded via inline-asm global_load_dwordx4;
// each row consumes after s_waitcnt vmcnt(7) + sched_barrier(0) and
// re-issues its slot. Cross-lane via DPP row_shr:1 + readlane boundary fix.
// Exact power-of-2 renorm every 8 rows. No LDS, no barriers, no
// transcendentals in the loop. LP over-allocated: tail prefetch harmless.
// ---------------------------------------------------------------------------
__global__ __launch_bounds__(64, 1) void ctc_scan_kernel(
    const unsigned short* __restrict__ pr,  // (B, T, LPROW) bf16: prob * 1024
    const int* __restrict__ targets, const int* __restrict__ inlens,
    const int* __restrict__ tlens, float* __restrict__ partial,
    int T, int B, int L, int S)
{
  const int b = blockIdx.x;
  const int lane = threadIdx.x;
  const int s0 = lane * 5;
  const int inlen = inlens[b];
  const int tlen = tlens[b];
  const int send = 2 * tlen;
  const int capT = inlen - 1;
  const bool is16 = (lane == 16), is32 = (lane == 32), is48 = (lane == 48);

  const unsigned short* lpb = pr + (long)b * T * LPROW + lane * 8;

  float skm[5];  // skip multiplier 0/1
#pragma unroll
  for (int j = 0; j < 5; ++j) {
    int s = s0 + j;
    float sk = 0.f;
    if (s < S && (s & 1) && s >= 3) {
      int lab = targets[b * L + (s >> 1)];
      int lab2 = targets[b * L + (s >> 1) - 1];
      sk = ((lab != 0) && (lab != lab2)) ? 1.f : 0.f;
    }
    skm[j] = sk;
  }

  // init alpha' from row 0 (plain load; pad states hold 0 in LP)
  float a[5];
  float abv = 0.f, alv = 0.f;
  int corr = 0, corr_cap = 0;
#pragma unroll
  for (int j = 0; j < 5; ++j) {
    int s = s0 + j;
    a[j] = (s <= 1) ? b2f(lpb[j]) : 0.f;
  }
  if (capT == 0) {
#pragma unroll
    for (int j = 0; j < 5; ++j) {
      int s = s0 + j;
      if (s == send) abv = a[j];
      if (s == send - 1) alv = a[j];
    }
    corr_cap = corr;
  }

#define CTC_WAIT                                          \
  do {                                                    \
    asm volatile("s_waitcnt vmcnt(7)" ::: "memory");      \
    __builtin_amdgcn_sched_barrier(0);                    \
  } while (0)

  // one DP row from a raw u32x4 of 8 bf16 (shift/mask -> f32).
#define CTC_PROCESS(rd, tcur)                                                 \
  do {                                                                        \
    float p0 = __uint_as_float((rd)[0] << 16);                                \
    float p1 = __uint_as_float((rd)[0] & 0xffff0000u);                        \
    float p2 = __uint_as_float((rd)[1] << 16);                                \
    float p3 = __uint_as_float((rd)[1] & 0xffff0000u);                        \
    float p4 = __uint_as_float((rd)[2] << 16);                                \
    float r15 = readlane_f(a[4], 15), r31 = readlane_f(a[4], 31),             \
          r47 = readlane_f(a[4], 47);                                         \
    float q15 = readlane_f(a[3], 15), q31 = readlane_f(a[3], 31),             \
          q47 = readlane_f(a[3], 47);                                         \
    float o_m1 = dpp_shr<1>(a[4]);                                            \
    float o_m2 = dpp_shr<1>(a[3]);                                            \
    o_m1 = is16 ? r15 : o_m1; o_m1 = is32 ? r31 : o_m1;                       \
    o_m1 = is48 ? r47 : o_m1;                                                 \
    o_m2 = is16 ? q15 : o_m2; o_m2 = is32 ? q31 : o_m2;                       \
    o_m2 = is48 ? q47 : o_m2;                                                 \
    float na0 = fmaf(skm[0], o_m2, a[0] + o_m1) * p0;                         \
    float na1 = fmaf(skm[1], o_m1, a[1] + a[0]) * p1;                         \
    float na2 = fmaf(skm[2], a[0], a[2] + a[1]) * p2;                         \
    float na3 = fmaf(skm[3], a[1], a[3] + a[2]) * p3;                         \
    float na4 = fmaf(skm[4], a[2], a[4] + a[3]) * p4;                         \
    a[0] = na0; a[1] = na1; a[2] = na2; a[3] = na3; a[4] = na4;               \
    if ((tcur) == capT) {                                                     \
      _Pragma("unroll")                                                       \
      for (int j = 0; j < 5; ++j) {                                           \
        int s = s0 + j;                                                       \
        if (s == send) abv = a[j];                                            \
        if (s == send - 1) alv = a[j];                                        \
      }                                                                       \
      corr_cap = corr;                                                        \
    }                                                                         \
  } while (0)

  // exact power-of-2 wave renorm, VALU-only (DPP prefix-max + readlanes)
#define CTC_RENORM                                                            \
  do {                                                                        \
    float m_ = fmaxf(fmaxf(fmaxf(a[0], a[1]), fmaxf(a[2], a[3])), a[4]);      \
    m_ = fmaxf(m_, dpp_shr<1>(m_));                                           \
    m_ = fmaxf(m_, dpp_shr<2>(m_));                                           \
    m_ = fmaxf(m_, dpp_shr<4>(m_));                                           \
    m_ = fmaxf(m_, dpp_shr<8>(m_));                                           \
    float mx = fmaxf(fmaxf(readlane_f(m_, 15), readlane_f(m_, 31)),           \
                     fmaxf(readlane_f(m_, 47), readlane_f(m_, 63)));          \
    int e;                                                                    \
    (void)frexpf(mx, &e);  /* mx == 0 -> e = 0 -> no-op */                    \
    float sc = ldexpf(1.f, -e);                                               \
    _Pragma("unroll")                                                         \
    for (int j = 0; j < 5; ++j) a[j] *= sc;                                   \
    corr += e;                                                                \
  } while (0)

// consume slot gN (row t), then re-issue it for row t+8
#define CTC_STEP(gN)                                          \
  do {                                                        \
    CTC_WAIT;                                                 \
    if (t < T) CTC_PROCESS(gN, t);                            \
    gN = gload_x4(lpb + (long)(t + 8) * LPROW);               \
    ++t;                                                      \
  } while (0)

  // prologue: 8 named slots, rows 1..8 (issue order pinned by asm volatile)
  u32x4 g0 = gload_x4(lpb + (long)1 * LPROW);
  u32x4 g1 = gload_x4(lpb + (long)2 * LPROW);
  u32x4 g2 = gload_x4(lpb + (long)3 * LPROW);
  u32x4 g3 = gload_x4(lpb + (long)4 * LPROW);
  u32x4 g4 = gload_x4(lpb + (long)5 * LPROW);
  u32x4 g5 = gload_x4(lpb + (long)6 * LPROW);
  u32x4 g6 = gload_x4(lpb + (long)7 * LPROW);
  u32x4 g7 = gload_x4(lpb + (long)8 * LPROW);

  const int NCH = (T - 1 + 7) / 8;
  int t = 1;
  for (int c = 0; c < NCH; ++c) {
    CTC_STEP(g0);
    CTC_STEP(g1);
    CTC_STEP(g2);
    CTC_STEP(g3);
    CTC_STEP(g4);
    CTC_STEP(g5);
    CTC_STEP(g6);
    CTC_STEP(g7);
    CTC_RENORM;
  }
  asm volatile("s_waitcnt vmcnt(0)" ::: "memory");

  // reduce the (single-lane-held) captures across the wave (one-time)
#pragma unroll
  for (int off = 32; off; off >>= 1) {
    abv = fmaxf(abv, __shfl_xor(abv, off));
    alv = fmaxf(alv, __shfl_xor(alv, off));
  }
  if (lane == 0) {
    // true log2(alpha) = log2(alpha') + corr_cap - 10*inlen
    float l2 = fast_log2(abv + alv) + (float)corr_cap - 10.0f * (float)inlen;
    float loss = -LN2 * l2;
    if (!(loss <= 1e29f)) loss = 0.f;  // zero_infinity (also catches NaN)
    partial[b] = loss / (float)tlen;
  }
}

__global__ void reduce_kernel(const float* __restrict__ partial,
                              float* __restrict__ out, int B)
{
  int lane = threadIdx.x;
  float v = (lane < B) ? partial[lane] : 0.f;
#pragma unroll
  for (int off = 32; off; off >>= 1) v += __shfl_xor(v, off);
  if (lane == 0) out[0] = v / (float)B;
}

// ---------------------------------------------------------------------------
extern "C" void kernel_launch(void* const* d_in, const int* in_sizes, int n_in,
                              void* d_out, int out_size, void* d_ws, size_t ws_size,
                              hipStream_t stream) {
  const float* enc = (const float*)d_in[0];
  const float* Wp  = (const float*)d_in[1];
  const float* bp  = (const float*)d_in[2];
  const float* Wt  = (const float*)d_in[3];
  const float* btr = (const float*)d_in[4];
  const float* lng = (const float*)d_in[5];
  const float* lnb = (const float*)d_in[6];
  const float* Wd  = (const float*)d_in[7];
  const float* bd  = (const float*)d_in[8];
  const int* tgt   = (const int*)d_in[9];
  const int* inl   = (const int*)d_in[10];
  const int* tll   = (const int*)d_in[11];

  const int D = in_sizes[2];              // 768
  const int V = in_sizes[8];              // 1024
  const int B = in_sizes[10];             // 32
  const int L = in_sizes[9] / B;          // 150
  const long M = (long)in_sizes[0] / D;   // T*B = 64000
  const int T = (int)(M / B);             // 2000
  const int S = 2 * L + 1;                // 301

  char* wsb = (char*)d_ws;
  size_t off = 0;
  auto alloc = [&](size_t bytes) { char* p = wsb + off; off += (bytes + 255) & ~(size_t)255; return p; };
  unsigned short* encb   = (unsigned short*)alloc((size_t)M * D * 2);
  char* x1region         = alloc((size_t)M * V * 2);
  unsigned short* X1b    = (unsigned short*)x1region;   // dead after gemm2
  unsigned short* scores = (unsigned short*)x1region;   // written by gemm3
  unsigned short* X2b    = encb;                        // encb dead after gemm1
  // +64KB slack: ctc tail prefetch reads up to 8 rows past the end
  unsigned short* LP     = (unsigned short*)alloc((size_t)B * T * LPROW * 2 + 65536);
  float2* partials       = (float2*)alloc((size_t)M * 16 * sizeof(float2));
  unsigned short* WpT    = (unsigned short*)alloc((size_t)D * D * 2);
  unsigned short* WtT    = (unsigned short*)alloc((size_t)D * D * 2);
  unsigned short* WdT    = (unsigned short*)alloc((size_t)D * V * 2);
  float* partial         = (float*)alloc(256);

  cvt_wt_kernel<<<dim3(D / 32, D / 32), dim3(32, 8), 0, stream>>>(Wp, WpT, D, D);
  cvt_wt_kernel<<<dim3(D / 32, D / 32), dim3(32, 8), 0, stream>>>(Wt, WtT, D, D);
  cvt_wt_kernel<<<dim3(V / 32, D / 32), dim3(32, 8), 0, stream>>>(Wd, WdT, D, V);
  cvt_enc_kernel<<<2048, 256, 0, stream>>>(enc, encb, (long)M * D / 4);

  const size_t smemg = 34816;
  const int gx12 = D / 128, nwg12 = gx12 * (int)(M / 128);  // 6*500 = 3000
  const int gx3 = V / 128, nwg3 = gx3 * (int)(M / 128);     // 8*500 = 4000

  gemm128_kernel<768, 0><<<nwg12, 256, smemg, stream>>>(
      encb, WpT, bp, X1b, nullptr, D, gx12, nwg12);
  gemm128_kernel<768, 1><<<nwg12, 256, smemg, stream>>>(
      X1b, WtT, btr, X2b, nullptr, D, gx12, nwg12);
  ln_bf16_kernel<768><<<(int)(M / 4), 256, 0, stream>>>(X2b, lng, lnb, M);
  gemm128_kernel<1024, 2><<<nwg3, 256, smemg, stream>>>(
      X2b, WdT, bd, scores, partials, D, gx3, nwg3);

  logz_gather_kernel<<<(int)(M / 4), 256, 0, stream>>>(
      scores, partials, tgt, LP, M, T, B, L, S);
  ctc_scan_kernel<<<B, 64, 0, stream>>>(LP, tgt, inl, tll, partial, T, B, L, S);
  reduce_kernel<<<1, 64, 0, stream>>>(partial, (float*)d_out, B);
}